// Round 11
// baseline (522.467 us; speedup 1.0000x reference)
//
#include <hip/hip_runtime.h>

#define N_NODES 50000
#define N_EDGES 500000
#define D 256
#define TWO_D 512

typedef __attribute__((ext_vector_type(8))) __bf16 bf16x8;
typedef __attribute__((ext_vector_type(4))) float f32x4;
typedef unsigned short ushort_t;

__device__ __forceinline__ unsigned short f2bf(float f) {
    unsigned int u = __builtin_bit_cast(unsigned int, f);
    u += 0x7FFFu + ((u >> 16) & 1u);   // round-to-nearest-even
    return (unsigned short)(u >> 16);
}
__device__ __forceinline__ unsigned int pk2(float lo, float hi) {
    return (unsigned int)f2bf(lo) | ((unsigned int)f2bf(hi) << 16);
}
__device__ __forceinline__ float bf2f(ushort_t u) {
    return __builtin_bit_cast(float, ((unsigned int)u) << 16);
}

// ---------------- prep kernels ----------------

__global__ void k_zero(float* __restrict__ p, int n4) {
    int i = blockIdx.x * blockDim.x + threadIdx.x;
    if (i < n4) ((float4*)p)[i] = make_float4(0.f, 0.f, 0.f, 0.f);
}

__global__ void k_cvt_x(const float* __restrict__ x, ushort_t* __restrict__ xb, int n8) {
    int i = blockIdx.x * blockDim.x + threadIdx.x;
    if (i < n8) {
        const float4* s = (const float4*)(x + (size_t)i * 8);
        float4 a = s[0], b = s[1];
        uint4 o;
        o.x = pk2(a.x, a.y); o.y = pk2(a.z, a.w);
        o.z = pk2(b.x, b.y); o.w = pk2(b.z, b.w);
        *(uint4*)(xb + (size_t)i * 8) = o;
    }
}

// W slice [KW rows of D cols] f32 -> Wt [D][KW] bf16 (transposed)
__global__ void k_wt(const float* __restrict__ w, ushort_t* __restrict__ wt, int KW) {
    int n = blockIdx.x;
    for (int k = threadIdx.x; k < KW; k += blockDim.x)
        wt[(size_t)n * KW + k] = f2bf(w[(size_t)k * D + n]);
}

__global__ void k_count_i(const int* __restrict__ coli, int* __restrict__ cnt) {
    int e = blockIdx.x * blockDim.x + threadIdx.x;
    if (e < N_EDGES) atomicAdd(&cnt[coli[e]], 1);
}

// ---------------- CSR build ----------------

__device__ __forceinline__ int iscan_block(int v, int tid) {
    int lane = tid & 63, wv = tid >> 6;
    int s = v;
    #pragma unroll
    for (int off = 1; off < 64; off <<= 1) {
        int t = __shfl_up(s, off, 64);
        if (lane >= off) s += t;
    }
    __shared__ int wsum[4];
    if (lane == 63) wsum[wv] = s;
    __syncthreads();
    #pragma unroll
    for (int w = 0; w < 3; ++w)
        if (wv > w) s += wsum[w];
    return s;
}

__global__ void k_scan_a(const int* __restrict__ cnt, int* __restrict__ rowptr,
                         int* __restrict__ bsum) {
    int i = blockIdx.x * 256 + threadIdx.x;
    int v = (i < N_NODES) ? cnt[i] : 0;
    int s = iscan_block(v, threadIdx.x);
    if (i < N_NODES) rowptr[i] = s - v;
    if (threadIdx.x == 255) bsum[blockIdx.x] = s;
}

__global__ void k_scan_b(int* __restrict__ bsum, int nb) {
    int i = threadIdx.x;
    int v = (i < nb) ? bsum[i] : 0;
    int s = iscan_block(v, i);
    if (i < nb) bsum[i] = s - v;
}

__global__ void k_scan_c(int* __restrict__ rowptr, const int* __restrict__ bsum,
                         int* __restrict__ cursor) {
    int i = blockIdx.x * 256 + threadIdx.x;
    if (i < N_NODES) {
        int r = rowptr[i] + bsum[blockIdx.x];
        rowptr[i] = r;
        cursor[i] = r;
    }
    if (i == 0) rowptr[N_NODES] = N_EDGES;
}

// csrpos[e] = position of edge e in dest-node-grouped (CSR) order
__global__ void k_fill_pos(const int* __restrict__ coli, int* __restrict__ cursor,
                           int* __restrict__ csrpos) {
    int e = blockIdx.x * blockDim.x + threadIdx.x;
    if (e < N_EDGES)
        csrpos[e] = atomicAdd(&cursor[coli[e]], 1);
}

// ---------------- xw1 = x @ W1a + b1 (bf16 out, per node) ----------------
__global__ __launch_bounds__(256) void k_xw1(
    const ushort_t* __restrict__ xb, const ushort_t* __restrict__ w1at,
    const float* __restrict__ b1, ushort_t* __restrict__ xw1b)
{
    __shared__ __align__(16) ushort_t As[64 * 64];
    __shared__ __align__(16) ushort_t Bs[256 * 64];
    const int tid = threadIdx.x;
    const int wave = tid >> 6, lane = tid & 63;
    const int lr = lane & 15, lh = lane >> 4;
    const int n0 = blockIdx.x * 64;

    const int sm = tid >> 2;
    const int sc = (tid & 3) << 4;
    int ns = n0 + sm; if (ns >= N_NODES) ns = N_NODES - 1;
    const ushort_t* xrow = xb + (size_t)ns * D;
    const ushort_t* wrow = w1at + (size_t)tid * D;
    const int swA = (sm & 7) << 3;
    const int swB = (tid & 7) << 3;

    f32x4 acc[4][4];
    #pragma unroll
    for (int i = 0; i < 4; ++i)
        #pragma unroll
        for (int j = 0; j < 4; ++j)
            acc[i][j] = (f32x4){0.f, 0.f, 0.f, 0.f};

    for (int kk = 0; kk < 4; ++kk) {
        const int k0 = kk << 6;
        const uint4* sx = (const uint4*)(xrow + k0 + sc);
        uint4 av0 = sx[0], av1 = sx[1];
        const uint4* wsv = (const uint4*)(wrow + k0);
        uint4 w0 = wsv[0], w1 = wsv[1], w2 = wsv[2], w3 = wsv[3];
        uint4 w4 = wsv[4], w5 = wsv[5], w6 = wsv[6], w7 = wsv[7];

        __syncthreads();
        *(uint4*)&As[sm * 64 + ( sc      ^ swA)] = av0;
        *(uint4*)&As[sm * 64 + ((sc + 8) ^ swA)] = av1;
        {
            const int base = tid * 64;
            *(uint4*)&Bs[base + ( 0 ^ swB)] = w0;
            *(uint4*)&Bs[base + ( 8 ^ swB)] = w1;
            *(uint4*)&Bs[base + (16 ^ swB)] = w2;
            *(uint4*)&Bs[base + (24 ^ swB)] = w3;
            *(uint4*)&Bs[base + (32 ^ swB)] = w4;
            *(uint4*)&Bs[base + (40 ^ swB)] = w5;
            *(uint4*)&Bs[base + (48 ^ swB)] = w6;
            *(uint4*)&Bs[base + (56 ^ swB)] = w7;
        }
        __syncthreads();

        #pragma unroll
        for (int kh = 0; kh < 2; ++kh) {
            const int kb = kh * 32 + lh * 8;
            bf16x8 af[4], bfr[4];
            #pragma unroll
            for (int i = 0; i < 4; ++i) {
                int m = i * 16 + lr;
                af[i] = *(const bf16x8*)&As[m * 64 + (kb ^ ((m & 7) << 3))];
            }
            #pragma unroll
            for (int j = 0; j < 4; ++j) {
                int n = wave * 64 + j * 16 + lr;
                bfr[j] = *(const bf16x8*)&Bs[n * 64 + (kb ^ ((n & 7) << 3))];
            }
            #pragma unroll
            for (int i = 0; i < 4; ++i)
                #pragma unroll
                for (int j = 0; j < 4; ++j)
                    acc[i][j] = __builtin_amdgcn_mfma_f32_16x16x32_bf16(af[i], bfr[j], acc[i][j], 0, 0, 0);
        }
    }

    float bv[4];
    #pragma unroll
    for (int j = 0; j < 4; ++j) bv[j] = b1[wave * 64 + j * 16 + lr];
    #pragma unroll
    for (int i = 0; i < 4; ++i) {
        #pragma unroll
        for (int r = 0; r < 4; ++r) {
            int m = i * 16 + lh * 4 + r;
            int node = n0 + m;
            if (node < N_NODES) {
                ushort_t* orow = xw1b + (size_t)node * D + wave * 64 + lr;
                #pragma unroll
                for (int j = 0; j < 4; ++j)
                    orow[j * 16] = f2bf(acc[i][j][r] + bv[j]);
            }
        }
    }
}

// ---------------- edge GEMM, NATURAL order (K=256) ----------------
// Edges processed in natural order -> ea reads are fully COALESCED streams
// (the scattered-read wall from rounds 2-10 is gone). Proven R9 structure:
// XOR-LDS double buffer, one barrier per K-step, B direct from w1bt.
// Epilogue: h[csrpos[e]] = relu(acc + xw1[row[e]]) -- scatter-write at CSR
// position so k_agg can stream contiguously.
__global__ __launch_bounds__(256, 3) void k_edge_nat(
    const float* __restrict__ ea, const ushort_t* __restrict__ w1bt,
    const ushort_t* __restrict__ xw1b, const int* __restrict__ rowi,
    const int* __restrict__ csrpos, ushort_t* __restrict__ h)
{
    __shared__ __align__(16) ushort_t As[2][64 * 64];  // 2 x 8KB, ea tiles (bf16)
    const int tid = threadIdx.x;
    const int wave = tid >> 6, lane = tid & 63;
    const int lr = lane & 15, lh = lane >> 4;
    const int e0 = blockIdx.x * 64;

    const int sm = tid >> 2;           // A row staged by this thread
    const int sc = (tid & 3) << 4;     // 16-elem chunk within 64-elem K-step
    int es = e0 + sm; if (es >= N_EDGES) es = N_EDGES - 1;
    const float* earow = ea + (size_t)es * D;          // CONSECUTIVE rows -> coalesced
    const int swA = (sm & 7) << 3;

    // B row pointers: col n = wave*64 + j*16 + lr, pre-offset by lane k-phase
    const ushort_t* pw[4];
    #pragma unroll
    for (int j = 0; j < 4; ++j)
        pw[j] = w1bt + (size_t)(wave * 64 + j * 16 + lr) * D + lh * 8;

    f32x4 acc[4][4];
    #pragma unroll
    for (int i = 0; i < 4; ++i)
        #pragma unroll
        for (int j = 0; j < 4; ++j)
            acc[i][j] = (f32x4){0.f, 0.f, 0.f, 0.f};

    // ---- prologue: stage step 0, prefetch step 1 ----
    float4 a0, a1, a2, a3;
    {
        const float4* s = (const float4*)(earow + sc);
        a0 = s[0]; a1 = s[1]; a2 = s[2]; a3 = s[3];
    }
    {
        uint4 av0, av1;
        av0.x = pk2(a0.x, a0.y); av0.y = pk2(a0.z, a0.w);
        av0.z = pk2(a1.x, a1.y); av0.w = pk2(a1.z, a1.w);
        av1.x = pk2(a2.x, a2.y); av1.y = pk2(a2.z, a2.w);
        av1.z = pk2(a3.x, a3.y); av1.w = pk2(a3.z, a3.w);
        *(uint4*)&As[0][sm * 64 + ( sc      ^ swA)] = av0;
        *(uint4*)&As[0][sm * 64 + ((sc + 8) ^ swA)] = av1;
    }
    {
        const float4* s = (const float4*)(earow + 64 + sc);
        a0 = s[0]; a1 = s[1]; a2 = s[2]; a3 = s[3];
    }
    __syncthreads();

    // ---- K-loop: 4 steps of 64, double-buffered, one barrier per step ----
    #pragma unroll
    for (int kk = 0; kk < 4; ++kk) {
        const int k0 = kk << 6;
        const ushort_t* cur = As[kk & 1];

        bf16x8 b0[4], b1[4];
        #pragma unroll
        for (int j = 0; j < 4; ++j) {
            b0[j] = *(const bf16x8*)(pw[j] + k0);
            b1[j] = *(const bf16x8*)(pw[j] + k0 + 32);
        }
        bf16x8 af0[4], af1[4];
        #pragma unroll
        for (int i = 0; i < 4; ++i) {
            const int m = i * 16 + lr;
            const int sw = (m & 7) << 3;
            af0[i] = *(const bf16x8*)&cur[m * 64 + (( lh * 8     ) ^ sw)];
            af1[i] = *(const bf16x8*)&cur[m * 64 + ((32 + lh * 8) ^ sw)];
        }
        #pragma unroll
        for (int i = 0; i < 4; ++i)
            #pragma unroll
            for (int j = 0; j < 4; ++j) {
                acc[i][j] = __builtin_amdgcn_mfma_f32_16x16x32_bf16(af0[i], b0[j], acc[i][j], 0, 0, 0);
                acc[i][j] = __builtin_amdgcn_mfma_f32_16x16x32_bf16(af1[i], b1[j], acc[i][j], 0, 0, 0);
            }

        if (kk < 3) {
            uint4 av0, av1;
            av0.x = pk2(a0.x, a0.y); av0.y = pk2(a0.z, a0.w);
            av0.z = pk2(a1.x, a1.y); av0.w = pk2(a1.z, a1.w);
            av1.x = pk2(a2.x, a2.y); av1.y = pk2(a2.z, a2.w);
            av1.z = pk2(a3.x, a3.y); av1.w = pk2(a3.z, a3.w);
            ushort_t* nxt = (ushort_t*)As[(kk + 1) & 1];
            *(uint4*)&nxt[sm * 64 + ( sc      ^ swA)] = av0;
            *(uint4*)&nxt[sm * 64 + ((sc + 8) ^ swA)] = av1;
            if (kk < 2) {
                const float4* s = (const float4*)(earow + ((kk + 2) << 6) + sc);
                a0 = s[0]; a1 = s[1]; a2 = s[2]; a3 = s[3];
            }
            __syncthreads();
        }
    }

    // ---- epilogue: add gathered xw1[row[e]], relu, scatter-store to h[csrpos[e]] ----
    #pragma unroll
    for (int i = 0; i < 4; ++i) {
        #pragma unroll
        for (int r = 0; r < 4; ++r) {
            const int m = i * 16 + lh * 4 + r;
            const int e = e0 + m;
            if (e < N_EDGES) {
                const int srw = rowi[e];
                const ushort_t* xr = xw1b + (size_t)srw * D + wave * 64 + lr;
                const int p = csrpos[e];
                ushort_t* hrow = h + (size_t)p * D + wave * 64 + lr;
                #pragma unroll
                for (int j = 0; j < 4; ++j) {
                    float v = acc[i][j][r] + bf2f(xr[j * 16]);
                    hrow[j * 16] = f2bf(v > 0.f ? v : 0.f);
                }
            }
        }
    }
}

// ---------------- aggregation: contiguous mean of h rows per node ----------------
// h is in CSR order -> rows rowptr[n]..rowptr[n+1] are ADJACENT: pure stream.
__global__ __launch_bounds__(256) void k_agg(
    const ushort_t* __restrict__ h, const int* __restrict__ rowptr,
    ushort_t* __restrict__ aggb)
{
    int node = blockIdx.x * 4 + (threadIdx.x >> 6);
    if (node >= N_NODES) return;
    int lane = threadIdx.x & 63;
    int beg = rowptr[node], end = rowptr[node + 1];
    float a0 = 0.f, a1 = 0.f, a2 = 0.f, a3 = 0.f;
    const ushort_t* hp = h + (size_t)beg * D + lane * 4;
    for (int it = 0; it < end - beg; ++it) {
        ushort4 u = *(const ushort4*)(hp + (size_t)it * D);
        a0 += bf2f(u.x); a1 += bf2f(u.y); a2 += bf2f(u.z); a3 += bf2f(u.w);
    }
    float inv = 1.0f / fmaxf((float)(end - beg), 1.0f);
    ushort4 o;
    o.x = f2bf(a0 * inv); o.y = f2bf(a1 * inv);
    o.z = f2bf(a2 * inv); o.w = f2bf(a3 * inv);
    *(ushort4*)(aggb + (size_t)node * D + lane * 4) = o;
}

// ---------------- node GEMM ----------------
// out[i][n] = relu( concat(x[i], aggb[i]) @ W2 + b2 ) ; aggb bf16, pre-divided
__global__ __launch_bounds__(256) void k_node(
    const ushort_t* __restrict__ xb, const ushort_t* __restrict__ aggb,
    const ushort_t* __restrict__ w2t, const float* __restrict__ b2,
    float* __restrict__ out)
{
    __shared__ __align__(16) ushort_t As[64 * 64];
    __shared__ __align__(16) ushort_t Bs[256 * 64];
    const int tid = threadIdx.x;
    const int wave = tid >> 6, lane = tid & 63;
    const int lr = lane & 15, lh = lane >> 4;
    const int n0 = blockIdx.x * 64;

    const int sm = tid >> 2;
    const int sc = (tid & 3) << 4;
    int ns = n0 + sm; if (ns >= N_NODES) ns = N_NODES - 1;
    const ushort_t* xrow = xb   + (size_t)ns * D;
    const ushort_t* arow = aggb + (size_t)ns * D;
    const ushort_t* wrow = w2t  + (size_t)tid * TWO_D;
    const int swA = (sm & 7) << 3;
    const int swB = (tid & 7) << 3;

    f32x4 acc[4][4];
    #pragma unroll
    for (int i = 0; i < 4; ++i)
        #pragma unroll
        for (int j = 0; j < 4; ++j)
            acc[i][j] = (f32x4){0.f, 0.f, 0.f, 0.f};

    for (int kk = 0; kk < 8; ++kk) {
        const int k0 = kk << 6;
        uint4 av0, av1;
        if (kk < 4) {
            const uint4* s = (const uint4*)(xrow + k0 + sc);
            av0 = s[0]; av1 = s[1];
        } else {
            const uint4* s = (const uint4*)(arow + (k0 - D) + sc);
            av0 = s[0]; av1 = s[1];
        }
        const uint4* wsv = (const uint4*)(wrow + k0);
        uint4 w0 = wsv[0], w1 = wsv[1], w2 = wsv[2], w3 = wsv[3];
        uint4 w4 = wsv[4], w5 = wsv[5], w6 = wsv[6], w7 = wsv[7];

        __syncthreads();
        *(uint4*)&As[sm * 64 + ( sc      ^ swA)] = av0;
        *(uint4*)&As[sm * 64 + ((sc + 8) ^ swA)] = av1;
        {
            const int base = tid * 64;
            *(uint4*)&Bs[base + ( 0 ^ swB)] = w0;
            *(uint4*)&Bs[base + ( 8 ^ swB)] = w1;
            *(uint4*)&Bs[base + (16 ^ swB)] = w2;
            *(uint4*)&Bs[base + (24 ^ swB)] = w3;
            *(uint4*)&Bs[base + (32 ^ swB)] = w4;
            *(uint4*)&Bs[base + (40 ^ swB)] = w5;
            *(uint4*)&Bs[base + (48 ^ swB)] = w6;
            *(uint4*)&Bs[base + (56 ^ swB)] = w7;
        }
        __syncthreads();

        #pragma unroll
        for (int kh = 0; kh < 2; ++kh) {
            const int kb = kh * 32 + lh * 8;
            bf16x8 af[4], bfr[4];
            #pragma unroll
            for (int i = 0; i < 4; ++i) {
                int m = i * 16 + lr;
                af[i] = *(const bf16x8*)&As[m * 64 + (kb ^ ((m & 7) << 3))];
            }
            #pragma unroll
            for (int j = 0; j < 4; ++j) {
                int n = wave * 64 + j * 16 + lr;
                bfr[j] = *(const bf16x8*)&Bs[n * 64 + (kb ^ ((n & 7) << 3))];
            }
            #pragma unroll
            for (int i = 0; i < 4; ++i)
                #pragma unroll
                for (int j = 0; j < 4; ++j)
                    acc[i][j] = __builtin_amdgcn_mfma_f32_16x16x32_bf16(af[i], bfr[j], acc[i][j], 0, 0, 0);
        }
    }

    float bv[4];
    #pragma unroll
    for (int j = 0; j < 4; ++j) bv[j] = b2[wave * 64 + j * 16 + lr];
    #pragma unroll
    for (int i = 0; i < 4; ++i) {
        #pragma unroll
        for (int r = 0; r < 4; ++r) {
            int m = i * 16 + lh * 4 + r;
            int node = n0 + m;
            if (node < N_NODES) {
                float* orow = out + (size_t)node * D;
                #pragma unroll
                for (int j = 0; j < 4; ++j) {
                    float v = acc[i][j][r] + bv[j];
                    orow[wave * 64 + j * 16 + lr] = v > 0.f ? v : 0.f;
                }
            }
        }
    }
}

// ---------------- launch ----------------

extern "C" void kernel_launch(void* const* d_in, const int* in_sizes, int n_in,
                              void* d_out, int out_size, void* d_ws, size_t ws_size,
                              hipStream_t stream)
{
    const float* x  = (const float*)d_in[0];
    const int*   ei = (const int*)d_in[1];      // [2*E] int32: rows then cols
    const float* ea = (const float*)d_in[2];
    const float* W1 = (const float*)d_in[5];
    const float* b1 = (const float*)d_in[6];
    const float* W2 = (const float*)d_in[7];
    const float* b2 = (const float*)d_in[8];
    float* out = (float*)d_out;

    const int* rowi = ei;
    const int* coli = ei + N_EDGES;
    char* ws = (char*)d_ws;

    size_t off = 0;
    auto take = [&](size_t bytes) {
        char* p = ws + off;
        off = (off + bytes + 255) & ~(size_t)255;
        return p;
    };

    ushort_t* xb      = (ushort_t*)take((size_t)N_NODES * D * 2);   // 25.6 MB
    ushort_t* w1at    = (ushort_t*)take((size_t)D * D * 2);
    ushort_t* w1bt    = (ushort_t*)take((size_t)D * D * 2);
    ushort_t* w2t     = (ushort_t*)take((size_t)D * TWO_D * 2);
    ushort_t* xw1b    = (ushort_t*)take((size_t)N_NODES * D * 2);   // 25.6 MB (aliased by aggb)
    ushort_t* h       = (ushort_t*)take((size_t)N_EDGES * D * 2);   // 256 MB
    int*      cnti    = (int*)take(50016 * 4);
    int*      rowptr  = (int*)take(50016 * 4);
    int*      cursor  = (int*)take(50016 * 4);
    int*      bsum    = (int*)take(256 * 4);
    int*      csrpos  = (int*)take((size_t)N_EDGES * 4);            // 2 MB
    ushort_t* aggb    = xw1b;    // xw1b dead after k_edge_nat; reuse for aggb

    const int NB = (N_NODES + 255) / 256;          // 196
    const int EB = (N_EDGES + 255) / 256;          // 1954
    const int NGB = (N_NODES + 63) / 64;           // 782
    const int EGB = (N_EDGES + 63) / 64;           // 7813

    k_cvt_x<<<(N_NODES * D / 8 + 255) / 256, 256, 0, stream>>>(x, xb, N_NODES * D / 8);
    k_wt   <<<D, 256, 0, stream>>>(W1, w1at, D);
    k_wt   <<<D, 256, 0, stream>>>(W1 + (size_t)D * D, w1bt, D);
    k_wt   <<<D, 256, 0, stream>>>(W2, w2t, TWO_D);

    k_zero    <<<49, 256, 0, stream>>>((float*)cnti, 50016 / 4);
    k_count_i <<<EB, 256, 0, stream>>>(coli, cnti);
    k_scan_a  <<<NB, 256, 0, stream>>>(cnti, rowptr, bsum);
    k_scan_b  <<<1, 256, 0, stream>>>(bsum, NB);
    k_scan_c  <<<NB, 256, 0, stream>>>(rowptr, bsum, cursor);
    k_fill_pos<<<EB, 256, 0, stream>>>(coli, cursor, csrpos);

    k_xw1     <<<NGB, 256, 0, stream>>>(xb, w1at, b1, xw1b);
    k_edge_nat<<<EGB, 256, 0, stream>>>(ea, w1bt, xw1b, rowi, csrpos, h);
    k_agg     <<<(N_NODES + 3) / 4, 256, 0, stream>>>(h, rowptr, aggb);
    k_node    <<<NGB, 256, 0, stream>>>(xb, aggb, w2t, b2, out);
}

// Round 12
// 469.777 us; speedup vs baseline: 1.1122x; 1.1122x over previous
//
#include <hip/hip_runtime.h>

#define N_NODES 50000
#define N_EDGES 500000
#define D 256
#define TWO_D 512

typedef __attribute__((ext_vector_type(8))) __bf16 bf16x8;
typedef __attribute__((ext_vector_type(4))) float f32x4;
typedef unsigned short ushort_t;

__device__ __forceinline__ unsigned short f2bf(float f) {
    unsigned int u = __builtin_bit_cast(unsigned int, f);
    u += 0x7FFFu + ((u >> 16) & 1u);   // round-to-nearest-even
    return (unsigned short)(u >> 16);
}
__device__ __forceinline__ unsigned int pk2(float lo, float hi) {
    return (unsigned int)f2bf(lo) | ((unsigned int)f2bf(hi) << 16);
}

// Non-draining workgroup barrier: orders LDS ops (lgkmcnt) and synchronizes,
// but does NOT drain the global-load queue (vmcnt) like __syncthreads() does.
// This keeps prefetched global loads in flight ACROSS the barrier (T4).
__device__ __forceinline__ void barrier_nodrain() {
    asm volatile("s_waitcnt lgkmcnt(0)" ::: "memory");
    __builtin_amdgcn_s_barrier();
    __builtin_amdgcn_sched_barrier(0);
}

// ---------------- prep kernels ----------------

__global__ void k_zero(float* __restrict__ p, int n4) {
    int i = blockIdx.x * blockDim.x + threadIdx.x;
    if (i < n4) ((float4*)p)[i] = make_float4(0.f, 0.f, 0.f, 0.f);
}

__global__ void k_cvt_x(const float* __restrict__ x, ushort_t* __restrict__ xb, int n8) {
    int i = blockIdx.x * blockDim.x + threadIdx.x;
    if (i < n8) {
        const float4* s = (const float4*)(x + (size_t)i * 8);
        float4 a = s[0], b = s[1];
        uint4 o;
        o.x = pk2(a.x, a.y); o.y = pk2(a.z, a.w);
        o.z = pk2(b.x, b.y); o.w = pk2(b.z, b.w);
        *(uint4*)(xb + (size_t)i * 8) = o;
    }
}

// W slice [KW rows of D cols] f32 -> Wt [D][KW] bf16 (transposed)
__global__ void k_wt(const float* __restrict__ w, ushort_t* __restrict__ wt, int KW) {
    int n = blockIdx.x;
    for (int k = threadIdx.x; k < KW; k += blockDim.x)
        wt[(size_t)n * KW + k] = f2bf(w[(size_t)k * D + n]);
}

__global__ void k_count_i(const int* __restrict__ coli, int* __restrict__ cnt) {
    int e = blockIdx.x * blockDim.x + threadIdx.x;
    if (e < N_EDGES) atomicAdd(&cnt[coli[e]], 1);
}

// ---------------- CSR build ----------------

__device__ __forceinline__ int iscan_block(int v, int tid) {
    int lane = tid & 63, wv = tid >> 6;
    int s = v;
    #pragma unroll
    for (int off = 1; off < 64; off <<= 1) {
        int t = __shfl_up(s, off, 64);
        if (lane >= off) s += t;
    }
    __shared__ int wsum[4];
    if (lane == 63) wsum[wv] = s;
    __syncthreads();
    #pragma unroll
    for (int w = 0; w < 3; ++w)
        if (wv > w) s += wsum[w];
    return s;
}

__global__ void k_scan_a(const int* __restrict__ cnt, int* __restrict__ rowptr,
                         int* __restrict__ bsum) {
    int i = blockIdx.x * 256 + threadIdx.x;
    int v = (i < N_NODES) ? cnt[i] : 0;
    int s = iscan_block(v, threadIdx.x);
    if (i < N_NODES) rowptr[i] = s - v;
    if (threadIdx.x == 255) bsum[blockIdx.x] = s;
}

__global__ void k_scan_b(int* __restrict__ bsum, int nb) {
    int i = threadIdx.x;
    int v = (i < nb) ? bsum[i] : 0;
    int s = iscan_block(v, i);
    if (i < nb) bsum[i] = s - v;
}

__global__ void k_scan_c(int* __restrict__ rowptr, const int* __restrict__ bsum,
                         int* __restrict__ cursor) {
    int i = blockIdx.x * 256 + threadIdx.x;
    if (i < N_NODES) {
        int r = rowptr[i] + bsum[blockIdx.x];
        rowptr[i] = r;
        cursor[i] = r;
    }
    if (i == 0) rowptr[N_NODES] = N_EDGES;
}

__global__ void k_fill(const int* __restrict__ coli, const int* __restrict__ rowi,
                       int* __restrict__ cursor, int* __restrict__ elist,
                       int* __restrict__ rowg) {
    int e = blockIdx.x * blockDim.x + threadIdx.x;
    if (e < N_EDGES) {
        int p = atomicAdd(&cursor[coli[e]], 1);
        elist[p] = e;
        rowg[p] = rowi[e];
    }
}

// CSR position -> destination node (binary search over rowptr)
__global__ void k_posnode(const int* __restrict__ rowptr, int* __restrict__ posnode) {
    int p = blockIdx.x * blockDim.x + threadIdx.x;
    if (p >= N_EDGES) return;
    int lo = 0, hi = N_NODES;
    while (hi - lo > 1) {
        int mid = (lo + hi) >> 1;
        if (rowptr[mid] <= p) lo = mid; else hi = mid;
    }
    posnode[p] = lo;
}

// ---------------- xw1 = x @ W1a + b1 (f32 out, per node) ----------------
__global__ __launch_bounds__(256) void k_xw1(
    const ushort_t* __restrict__ xb, const ushort_t* __restrict__ w1at,
    const float* __restrict__ b1, float* __restrict__ xw1)
{
    __shared__ __align__(16) ushort_t As[64 * 64];
    __shared__ __align__(16) ushort_t Bs[256 * 64];
    const int tid = threadIdx.x;
    const int wave = tid >> 6, lane = tid & 63;
    const int lr = lane & 15, lh = lane >> 4;
    const int n0 = blockIdx.x * 64;

    const int sm = tid >> 2;
    const int sc = (tid & 3) << 4;
    int ns = n0 + sm; if (ns >= N_NODES) ns = N_NODES - 1;
    const ushort_t* xrow = xb + (size_t)ns * D;
    const ushort_t* wrow = w1at + (size_t)tid * D;
    const int swA = (sm & 7) << 3;
    const int swB = (tid & 7) << 3;

    f32x4 acc[4][4];
    #pragma unroll
    for (int i = 0; i < 4; ++i)
        #pragma unroll
        for (int j = 0; j < 4; ++j)
            acc[i][j] = (f32x4){0.f, 0.f, 0.f, 0.f};

    for (int kk = 0; kk < 4; ++kk) {
        const int k0 = kk << 6;
        const uint4* sx = (const uint4*)(xrow + k0 + sc);
        uint4 av0 = sx[0], av1 = sx[1];
        const uint4* wsv = (const uint4*)(wrow + k0);
        uint4 w0 = wsv[0], w1 = wsv[1], w2 = wsv[2], w3 = wsv[3];
        uint4 w4 = wsv[4], w5 = wsv[5], w6 = wsv[6], w7 = wsv[7];

        __syncthreads();
        *(uint4*)&As[sm * 64 + ( sc      ^ swA)] = av0;
        *(uint4*)&As[sm * 64 + ((sc + 8) ^ swA)] = av1;
        {
            const int base = tid * 64;
            *(uint4*)&Bs[base + ( 0 ^ swB)] = w0;
            *(uint4*)&Bs[base + ( 8 ^ swB)] = w1;
            *(uint4*)&Bs[base + (16 ^ swB)] = w2;
            *(uint4*)&Bs[base + (24 ^ swB)] = w3;
            *(uint4*)&Bs[base + (32 ^ swB)] = w4;
            *(uint4*)&Bs[base + (40 ^ swB)] = w5;
            *(uint4*)&Bs[base + (48 ^ swB)] = w6;
            *(uint4*)&Bs[base + (56 ^ swB)] = w7;
        }
        __syncthreads();

        #pragma unroll
        for (int kh = 0; kh < 2; ++kh) {
            const int kb = kh * 32 + lh * 8;
            bf16x8 af[4], bfr[4];
            #pragma unroll
            for (int i = 0; i < 4; ++i) {
                int m = i * 16 + lr;
                af[i] = *(const bf16x8*)&As[m * 64 + (kb ^ ((m & 7) << 3))];
            }
            #pragma unroll
            for (int j = 0; j < 4; ++j) {
                int n = wave * 64 + j * 16 + lr;
                bfr[j] = *(const bf16x8*)&Bs[n * 64 + (kb ^ ((n & 7) << 3))];
            }
            #pragma unroll
            for (int i = 0; i < 4; ++i)
                #pragma unroll
                for (int j = 0; j < 4; ++j)
                    acc[i][j] = __builtin_amdgcn_mfma_f32_16x16x32_bf16(af[i], bfr[j], acc[i][j], 0, 0, 0);
        }
    }

    float bv[4];
    #pragma unroll
    for (int j = 0; j < 4; ++j) bv[j] = b1[wave * 64 + j * 16 + lr];
    #pragma unroll
    for (int i = 0; i < 4; ++i) {
        #pragma unroll
        for (int r = 0; r < 4; ++r) {
            int m = i * 16 + lh * 4 + r;
            int node = n0 + m;
            if (node < N_NODES) {
                float* orow = xw1 + (size_t)node * D;
                #pragma unroll
                for (int j = 0; j < 4; ++j)
                    orow[wave * 64 + j * 16 + lr] = acc[i][j][r] + bv[j];
            }
        }
    }
}

// ---------------- edge GEMM (K=256) + in-register segmented aggregation ----------------
// R9 structure (best known: 313us) with ONE change: all K-loop barriers are
// non-draining (lgkmcnt(0) + raw s_barrier) so prefetched global loads stay in
// flight across barriers instead of being drained by __syncthreads' vmcnt(0).
__global__ __launch_bounds__(256, 3) void k_edge_csr(
    const float* __restrict__ ea, const ushort_t* __restrict__ w1bt,
    const float* __restrict__ xw1, const int* __restrict__ elist,
    const int* __restrict__ rowg, const int* __restrict__ posnode,
    const int* __restrict__ rowptr, float* __restrict__ agg)
{
    __shared__ __align__(16) ushort_t As[2][64 * 64];  // 2 x 8KB, ea tiles (bf16)
    __shared__ int snd[64];                            // dest node per tile row
    const int tid = threadIdx.x;
    const int wave = tid >> 6, lane = tid & 63;
    const int lr = lane & 15, lh = lane >> 4;
    const int p0 = blockIdx.x * 64;

    if (tid < 64) {
        int p = p0 + tid;
        snd[tid] = (p < N_EDGES) ? posnode[min(p, N_EDGES - 1)] : -1;
    }

    const int sm = tid >> 2;           // A row staged by this thread
    const int sc = (tid & 3) << 4;     // 16-elem chunk within 64-elem K-step
    int ps = p0 + sm; if (ps >= N_EDGES) ps = N_EDGES - 1;
    const float* earow = ea + (size_t)elist[ps] * D;
    const int swA = (sm & 7) << 3;

    // B row pointers: col n = wave*64 + j*16 + lr, pre-offset by lane k-phase
    const ushort_t* pw[4];
    #pragma unroll
    for (int j = 0; j < 4; ++j)
        pw[j] = w1bt + (size_t)(wave * 64 + j * 16 + lr) * D + lh * 8;

    f32x4 acc[4][4];
    #pragma unroll
    for (int i = 0; i < 4; ++i)
        #pragma unroll
        for (int j = 0; j < 4; ++j)
            acc[i][j] = (f32x4){0.f, 0.f, 0.f, 0.f};

    // ---- prologue: stage step 0, prefetch step 1 ----
    float4 a0, a1, a2, a3;
    {
        const float4* s = (const float4*)(earow + sc);
        a0 = s[0]; a1 = s[1]; a2 = s[2]; a3 = s[3];
    }
    {
        uint4 av0, av1;
        av0.x = pk2(a0.x, a0.y); av0.y = pk2(a0.z, a0.w);
        av0.z = pk2(a1.x, a1.y); av0.w = pk2(a1.z, a1.w);
        av1.x = pk2(a2.x, a2.y); av1.y = pk2(a2.z, a2.w);
        av1.z = pk2(a3.x, a3.y); av1.w = pk2(a3.z, a3.w);
        *(uint4*)&As[0][sm * 64 + ( sc      ^ swA)] = av0;
        *(uint4*)&As[0][sm * 64 + ((sc + 8) ^ swA)] = av1;
    }
    {
        const float4* s = (const float4*)(earow + 64 + sc);
        a0 = s[0]; a1 = s[1]; a2 = s[2]; a3 = s[3];
    }
    barrier_nodrain();                 // snd + buf0 visible; step-1 loads stay in flight

    // ---- K-loop: 4 steps of 64, double-buffered, one non-draining barrier per step ----
    #pragma unroll
    for (int kk = 0; kk < 4; ++kk) {
        const int k0 = kk << 6;
        const ushort_t* cur = As[kk & 1];

        // B fragments for this step (global, L1/L2-resident)
        bf16x8 b0[4], b1[4];
        #pragma unroll
        for (int j = 0; j < 4; ++j) {
            b0[j] = *(const bf16x8*)(pw[j] + k0);
            b1[j] = *(const bf16x8*)(pw[j] + k0 + 32);
        }
        // A fragments from LDS (proven XOR layout)
        bf16x8 af0[4], af1[4];
        #pragma unroll
        for (int i = 0; i < 4; ++i) {
            const int m = i * 16 + lr;
            const int sw = (m & 7) << 3;
            af0[i] = *(const bf16x8*)&cur[m * 64 + (( lh * 8     ) ^ sw)];
            af1[i] = *(const bf16x8*)&cur[m * 64 + ((32 + lh * 8) ^ sw)];
        }
        #pragma unroll
        for (int i = 0; i < 4; ++i)
            #pragma unroll
            for (int j = 0; j < 4; ++j) {
                acc[i][j] = __builtin_amdgcn_mfma_f32_16x16x32_bf16(af0[i], b0[j], acc[i][j], 0, 0, 0);
                acc[i][j] = __builtin_amdgcn_mfma_f32_16x16x32_bf16(af1[i], b1[j], acc[i][j], 0, 0, 0);
            }

        if (kk < 3) {
            // write prefetched step kk+1 into the other buffer
            uint4 av0, av1;
            av0.x = pk2(a0.x, a0.y); av0.y = pk2(a0.z, a0.w);
            av0.z = pk2(a1.x, a1.y); av0.w = pk2(a1.z, a1.w);
            av1.x = pk2(a2.x, a2.y); av1.y = pk2(a2.z, a2.w);
            av1.z = pk2(a3.x, a3.y); av1.w = pk2(a3.z, a3.w);
            ushort_t* nxt = (ushort_t*)As[(kk + 1) & 1];
            *(uint4*)&nxt[sm * 64 + ( sc      ^ swA)] = av0;
            *(uint4*)&nxt[sm * 64 + ((sc + 8) ^ swA)] = av1;
            if (kk < 2) {   // issue loads for step kk+2; they persist across the barrier
                const float4* s = (const float4*)(earow + ((kk + 2) << 6) + sc);
                a0 = s[0]; a1 = s[1]; a2 = s[2]; a3 = s[3];
            }
            barrier_nodrain();
        }
    }

    // ---- epilogue 1: add gathered xw1[src], relu, keep in registers ----
    #pragma unroll
    for (int i = 0; i < 4; ++i) {
        #pragma unroll
        for (int r = 0; r < 4; ++r) {
            const int m = i * 16 + lh * 4 + r;
            const bool ok = (p0 + m < N_EDGES);
            const int srw = rowg[min(p0 + m, N_EDGES - 1)];
            const float* xr = xw1 + (size_t)srw * D + wave * 64 + lr;
            #pragma unroll
            for (int j = 0; j < 4; ++j) {
                float v = acc[i][j][r] + xr[j * 16];
                v = v > 0.f ? v : 0.f;
                acc[i][j][r] = ok ? v : 0.f;
            }
        }
    }

    // ---- epilogue 2: block-uniform segment loop, in-register reduce (proven) ----
    int a = 0;
    while (a < 64) {
        const int node = snd[a];
        int b = a + 1;
        while (b < 64 && snd[b] == node) ++b;
        if (node >= 0) {
            float s0 = 0.f, s1 = 0.f, s2 = 0.f, s3 = 0.f;
            #pragma unroll
            for (int i = 0; i < 4; ++i) {
                if (b <= i * 16 || a >= (i + 1) * 16) continue;  // uniform skip
                #pragma unroll
                for (int r = 0; r < 4; ++r) {
                    const int m = i * 16 + lh * 4 + r;
                    const bool in = (m >= a) && (m < b);
                    s0 += in ? acc[i][0][r] : 0.f;
                    s1 += in ? acc[i][1][r] : 0.f;
                    s2 += in ? acc[i][2][r] : 0.f;
                    s3 += in ? acc[i][3][r] : 0.f;
                }
            }
            // fold the 4 lh groups (lanes differ in bits 4,5)
            s0 += __shfl_xor(s0, 16, 64); s0 += __shfl_xor(s0, 32, 64);
            s1 += __shfl_xor(s1, 16, 64); s1 += __shfl_xor(s1, 32, 64);
            s2 += __shfl_xor(s2, 16, 64); s2 += __shfl_xor(s2, 32, 64);
            s3 += __shfl_xor(s3, 16, 64); s3 += __shfl_xor(s3, 32, 64);
            if (lh == 0) {
                const bool interior = (rowptr[node] >= p0) && (rowptr[node + 1] <= p0 + 64);
                float* dst = agg + (size_t)node * D + wave * 64 + lr;
                if (interior) {
                    dst[0]  = s0; dst[16] = s1; dst[32] = s2; dst[48] = s3;
                } else {
                    atomicAdd(&dst[0],  s0); atomicAdd(&dst[16], s1);
                    atomicAdd(&dst[32], s2); atomicAdd(&dst[48], s3);
                }
            }
        }
        a = b;
    }
}

// ---------------- node GEMM ----------------
// out[i][n] = relu( concat(x[i], agg[i]/max(cnt,1)) @ W2 + b2 )
// Same non-draining-barrier treatment (single-buffer, 2 barriers per step).
__global__ __launch_bounds__(256) void k_node(
    const ushort_t* __restrict__ xb, const float* __restrict__ agg,
    const int* __restrict__ cnti,
    const ushort_t* __restrict__ w2t, const float* __restrict__ b2,
    float* __restrict__ out)
{
    __shared__ __align__(16) ushort_t As[64 * 64];
    __shared__ __align__(16) ushort_t Bs[256 * 64];
    const int tid = threadIdx.x;
    const int wave = tid >> 6, lane = tid & 63;
    const int lr = lane & 15, lh = lane >> 4;
    const int n0 = blockIdx.x * 64;

    const int sm = tid >> 2;
    const int sc = (tid & 3) << 4;
    int ns = n0 + sm; if (ns >= N_NODES) ns = N_NODES - 1;
    const ushort_t* xrow = xb + (size_t)ns * D;
    const float*    arow = agg + (size_t)ns * D;
    const float     ic   = 1.0f / fmaxf((float)cnti[ns], 1.0f);
    const ushort_t* wrow = w2t + (size_t)tid * TWO_D;
    const int swA = (sm & 7) << 3;
    const int swB = (tid & 7) << 3;

    f32x4 acc[4][4];
    #pragma unroll
    for (int i = 0; i < 4; ++i)
        #pragma unroll
        for (int j = 0; j < 4; ++j)
            acc[i][j] = (f32x4){0.f, 0.f, 0.f, 0.f};

    for (int kk = 0; kk < 8; ++kk) {
        const int k0 = kk << 6;
        uint4 av0, av1;
        if (kk < 4) {
            const uint4* s = (const uint4*)(xrow + k0 + sc);
            av0 = s[0]; av1 = s[1];
        } else {
            const float4* s = (const float4*)(arow + (k0 - D) + sc);
            float4 f0 = s[0], f1 = s[1], f2 = s[2], f3 = s[3];
            f0.x *= ic; f0.y *= ic; f0.z *= ic; f0.w *= ic;
            f1.x *= ic; f1.y *= ic; f1.z *= ic; f1.w *= ic;
            f2.x *= ic; f2.y *= ic; f2.z *= ic; f2.w *= ic;
            f3.x *= ic; f3.y *= ic; f3.z *= ic; f3.w *= ic;
            av0.x = pk2(f0.x, f0.y); av0.y = pk2(f0.z, f0.w);
            av0.z = pk2(f1.x, f1.y); av0.w = pk2(f1.z, f1.w);
            av1.x = pk2(f2.x, f2.y); av1.y = pk2(f2.z, f2.w);
            av1.z = pk2(f3.x, f3.y); av1.w = pk2(f3.z, f3.w);
        }
        const uint4* wsv = (const uint4*)(wrow + k0);
        uint4 w0 = wsv[0], w1 = wsv[1], w2 = wsv[2], w3 = wsv[3];
        uint4 w4 = wsv[4], w5 = wsv[5], w6 = wsv[6], w7 = wsv[7];

        barrier_nodrain();
        *(uint4*)&As[sm * 64 + ( sc      ^ swA)] = av0;
        *(uint4*)&As[sm * 64 + ((sc + 8) ^ swA)] = av1;
        {
            const int base = tid * 64;
            *(uint4*)&Bs[base + ( 0 ^ swB)] = w0;
            *(uint4*)&Bs[base + ( 8 ^ swB)] = w1;
            *(uint4*)&Bs[base + (16 ^ swB)] = w2;
            *(uint4*)&Bs[base + (24 ^ swB)] = w3;
            *(uint4*)&Bs[base + (32 ^ swB)] = w4;
            *(uint4*)&Bs[base + (40 ^ swB)] = w5;
            *(uint4*)&Bs[base + (48 ^ swB)] = w6;
            *(uint4*)&Bs[base + (56 ^ swB)] = w7;
        }
        barrier_nodrain();

        #pragma unroll
        for (int kh = 0; kh < 2; ++kh) {
            const int kb = kh * 32 + lh * 8;
            bf16x8 af[4], bfr[4];
            #pragma unroll
            for (int i = 0; i < 4; ++i) {
                int m = i * 16 + lr;
                af[i] = *(const bf16x8*)&As[m * 64 + (kb ^ ((m & 7) << 3))];
            }
            #pragma unroll
            for (int j = 0; j < 4; ++j) {
                int n = wave * 64 + j * 16 + lr;
                bfr[j] = *(const bf16x8*)&Bs[n * 64 + (kb ^ ((n & 7) << 3))];
            }
            #pragma unroll
            for (int i = 0; i < 4; ++i)
                #pragma unroll
                for (int j = 0; j < 4; ++j)
                    acc[i][j] = __builtin_amdgcn_mfma_f32_16x16x32_bf16(af[i], bfr[j], acc[i][j], 0, 0, 0);
        }
    }

    float bv[4];
    #pragma unroll
    for (int j = 0; j < 4; ++j) bv[j] = b2[wave * 64 + j * 16 + lr];
    #pragma unroll
    for (int i = 0; i < 4; ++i) {
        #pragma unroll
        for (int r = 0; r < 4; ++r) {
            int m = i * 16 + lh * 4 + r;
            int node = n0 + m;
            if (node < N_NODES) {
                float* orow = out + (size_t)node * D;
                #pragma unroll
                for (int j = 0; j < 4; ++j) {
                    float v = acc[i][j][r] + bv[j];
                    orow[wave * 64 + j * 16 + lr] = v > 0.f ? v : 0.f;
                }
            }
        }
    }
}

// ---------------- launch ----------------

extern "C" void kernel_launch(void* const* d_in, const int* in_sizes, int n_in,
                              void* d_out, int out_size, void* d_ws, size_t ws_size,
                              hipStream_t stream)
{
    const float* x  = (const float*)d_in[0];
    const int*   ei = (const int*)d_in[1];      // [2*E] int32: rows then cols
    const float* ea = (const float*)d_in[2];
    const float* W1 = (const float*)d_in[5];
    const float* b1 = (const float*)d_in[6];
    const float* W2 = (const float*)d_in[7];
    const float* b2 = (const float*)d_in[8];
    float* out = (float*)d_out;

    const int* rowi = ei;
    const int* coli = ei + N_EDGES;
    char* ws = (char*)d_ws;

    size_t off = 0;
    auto take = [&](size_t bytes) {
        char* p = ws + off;
        off = (off + bytes + 255) & ~(size_t)255;
        return p;
    };

    ushort_t* xb      = (ushort_t*)take((size_t)N_NODES * D * 2);
    ushort_t* w1at    = (ushort_t*)take((size_t)D * D * 2);
    ushort_t* w1bt    = (ushort_t*)take((size_t)D * D * 2);
    ushort_t* w2t     = (ushort_t*)take((size_t)D * TWO_D * 2);
    float*    xw1     = (float*)take((size_t)N_NODES * D * 4);
    float*    agg     = (float*)take((size_t)N_NODES * D * 4);
    int*      cnti    = (int*)take(50016 * 4);
    int*      rowptr  = (int*)take(50016 * 4);
    int*      cursor  = (int*)take(50016 * 4);
    int*      bsum    = (int*)take(256 * 4);
    int*      elist   = (int*)take((size_t)N_EDGES * 4);
    int*      rowg    = (int*)take((size_t)N_EDGES * 4);
    int*      posnode = (int*)take((size_t)N_EDGES * 4);

    const int NB = (N_NODES + 255) / 256;          // 196
    const int EB = (N_EDGES + 255) / 256;          // 1954
    const int NGB = (N_NODES + 63) / 64;           // 782
    const int EGB = (N_EDGES + 63) / 64;           // 7813

    k_cvt_x<<<(N_NODES * D / 8 + 255) / 256, 256, 0, stream>>>(x, xb, N_NODES * D / 8);
    k_wt   <<<D, 256, 0, stream>>>(W1, w1at, D);
    k_wt   <<<D, 256, 0, stream>>>(W1 + (size_t)D * D, w1bt, D);
    k_wt   <<<D, 256, 0, stream>>>(W2, w2t, TWO_D);

    k_zero   <<<49, 256, 0, stream>>>((float*)cnti, 50016 / 4);
    k_count_i<<<EB, 256, 0, stream>>>(coli, cnti);
    k_scan_a <<<NB, 256, 0, stream>>>(cnti, rowptr, bsum);
    k_scan_b <<<1, 256, 0, stream>>>(bsum, NB);
    k_scan_c <<<NB, 256, 0, stream>>>(rowptr, bsum, cursor);
    k_fill   <<<EB, 256, 0, stream>>>(coli, rowi, cursor, elist, rowg);
    k_posnode<<<EB, 256, 0, stream>>>(rowptr, posnode);

    k_xw1    <<<NGB, 256, 0, stream>>>(xb, w1at, b1, xw1);
    k_zero   <<<(N_NODES * D / 4 + 255) / 256, 256, 0, stream>>>(agg, N_NODES * D / 4);
    k_edge_csr<<<EGB, 256, 0, stream>>>(ea, w1bt, xw1, elist, rowg, posnode, rowptr, agg);
    k_node   <<<NGB, 256, 0, stream>>>(xb, agg, cnti, w2t, b2, out);
}

// Round 13
// 465.954 us; speedup vs baseline: 1.1213x; 1.0082x over previous
//
#include <hip/hip_runtime.h>

#define N_NODES 50000
#define N_EDGES 500000
#define D 256
#define TWO_D 512

typedef __attribute__((ext_vector_type(8))) __bf16 bf16x8;
typedef __attribute__((ext_vector_type(4))) float f32x4;
typedef unsigned short ushort_t;

__device__ __forceinline__ unsigned short f2bf(float f) {
    unsigned int u = __builtin_bit_cast(unsigned int, f);
    u += 0x7FFFu + ((u >> 16) & 1u);   // round-to-nearest-even
    return (unsigned short)(u >> 16);
}
__device__ __forceinline__ unsigned int pk2(float lo, float hi) {
    return (unsigned int)f2bf(lo) | ((unsigned int)f2bf(hi) << 16);
}

// Non-draining workgroup barrier (orders LDS, does not drain vmcnt).
__device__ __forceinline__ void barrier_nodrain() {
    asm volatile("s_waitcnt lgkmcnt(0)" ::: "memory");
    __builtin_amdgcn_s_barrier();
    __builtin_amdgcn_sched_barrier(0);
}

// ---------------- prep kernels ----------------

__global__ void k_zero(float* __restrict__ p, int n4) {
    int i = blockIdx.x * blockDim.x + threadIdx.x;
    if (i < n4) ((float4*)p)[i] = make_float4(0.f, 0.f, 0.f, 0.f);
}

__global__ void k_cvt_x(const float* __restrict__ x, ushort_t* __restrict__ xb, int n8) {
    int i = blockIdx.x * blockDim.x + threadIdx.x;
    if (i < n8) {
        const float4* s = (const float4*)(x + (size_t)i * 8);
        float4 a = s[0], b = s[1];
        uint4 o;
        o.x = pk2(a.x, a.y); o.y = pk2(a.z, a.w);
        o.z = pk2(b.x, b.y); o.w = pk2(b.z, b.w);
        *(uint4*)(xb + (size_t)i * 8) = o;
    }
}

// W slice [KW rows of D cols] f32 -> Wt [D][KW] bf16 (transposed)
__global__ void k_wt(const float* __restrict__ w, ushort_t* __restrict__ wt, int KW) {
    int n = blockIdx.x;
    for (int k = threadIdx.x; k < KW; k += blockDim.x)
        wt[(size_t)n * KW + k] = f2bf(w[(size_t)k * D + n]);
}

__global__ void k_count_i(const int* __restrict__ coli, int* __restrict__ cnt) {
    int e = blockIdx.x * blockDim.x + threadIdx.x;
    if (e < N_EDGES) atomicAdd(&cnt[coli[e]], 1);
}

// ---------------- CSR build ----------------

__device__ __forceinline__ int iscan_block(int v, int tid) {
    int lane = tid & 63, wv = tid >> 6;
    int s = v;
    #pragma unroll
    for (int off = 1; off < 64; off <<= 1) {
        int t = __shfl_up(s, off, 64);
        if (lane >= off) s += t;
    }
    __shared__ int wsum[4];
    if (lane == 63) wsum[wv] = s;
    __syncthreads();
    #pragma unroll
    for (int w = 0; w < 3; ++w)
        if (wv > w) s += wsum[w];
    return s;
}

__global__ void k_scan_a(const int* __restrict__ cnt, int* __restrict__ rowptr,
                         int* __restrict__ bsum) {
    int i = blockIdx.x * 256 + threadIdx.x;
    int v = (i < N_NODES) ? cnt[i] : 0;
    int s = iscan_block(v, threadIdx.x);
    if (i < N_NODES) rowptr[i] = s - v;
    if (threadIdx.x == 255) bsum[blockIdx.x] = s;
}

__global__ void k_scan_b(int* __restrict__ bsum, int nb) {
    int i = threadIdx.x;
    int v = (i < nb) ? bsum[i] : 0;
    int s = iscan_block(v, i);
    if (i < nb) bsum[i] = s - v;
}

__global__ void k_scan_c(int* __restrict__ rowptr, const int* __restrict__ bsum,
                         int* __restrict__ cursor) {
    int i = blockIdx.x * 256 + threadIdx.x;
    if (i < N_NODES) {
        int r = rowptr[i] + bsum[blockIdx.x];
        rowptr[i] = r;
        cursor[i] = r;
    }
    if (i == 0) rowptr[N_NODES] = N_EDGES;
}

__global__ void k_fill(const int* __restrict__ coli, const int* __restrict__ rowi,
                       int* __restrict__ cursor, int* __restrict__ elist,
                       int* __restrict__ rowg) {
    int e = blockIdx.x * blockDim.x + threadIdx.x;
    if (e < N_EDGES) {
        int p = atomicAdd(&cursor[coli[e]], 1);
        elist[p] = e;
        rowg[p] = rowi[e];
    }
}

// CSR position -> packed (node<<1)|interior, where interior = this node's whole
// segment lies inside p's 64-edge tile (so the tile can plain-store, no atomic).
__global__ void k_posnode(const int* __restrict__ rowptr, int* __restrict__ posnode) {
    int p = blockIdx.x * blockDim.x + threadIdx.x;
    if (p >= N_EDGES) return;
    int lo = 0, hi = N_NODES;
    while (hi - lo > 1) {
        int mid = (lo + hi) >> 1;
        if (rowptr[mid] <= p) lo = mid; else hi = mid;
    }
    const int t0 = p & ~63;
    const int inter = (rowptr[lo] >= t0) && (rowptr[lo + 1] <= t0 + 64);
    posnode[p] = (lo << 1) | inter;
}

// ---------------- xw1 = x @ W1a + b1 (f32, fragment-permuted layout) ----------------
// Layout: xw1[node*D + (wave*16+lr)*4 + j] holds column (wave*64 + j*16 + lr).
// This makes k_edge's per-(i,r) gather a single float4 load.
__global__ __launch_bounds__(256) void k_xw1(
    const ushort_t* __restrict__ xb, const ushort_t* __restrict__ w1at,
    const float* __restrict__ b1, float* __restrict__ xw1)
{
    __shared__ __align__(16) ushort_t As[64 * 64];
    __shared__ __align__(16) ushort_t Bs[256 * 64];
    const int tid = threadIdx.x;
    const int wave = tid >> 6, lane = tid & 63;
    const int lr = lane & 15, lh = lane >> 4;
    const int n0 = blockIdx.x * 64;

    const int sm = tid >> 2;
    const int sc = (tid & 3) << 4;
    int ns = n0 + sm; if (ns >= N_NODES) ns = N_NODES - 1;
    const ushort_t* xrow = xb + (size_t)ns * D;
    const ushort_t* wrow = w1at + (size_t)tid * D;
    const int swA = (sm & 7) << 3;
    const int swB = (tid & 7) << 3;

    f32x4 acc[4][4];
    #pragma unroll
    for (int i = 0; i < 4; ++i)
        #pragma unroll
        for (int j = 0; j < 4; ++j)
            acc[i][j] = (f32x4){0.f, 0.f, 0.f, 0.f};

    for (int kk = 0; kk < 4; ++kk) {
        const int k0 = kk << 6;
        const uint4* sx = (const uint4*)(xrow + k0 + sc);
        uint4 av0 = sx[0], av1 = sx[1];
        const uint4* wsv = (const uint4*)(wrow + k0);
        uint4 w0 = wsv[0], w1 = wsv[1], w2 = wsv[2], w3 = wsv[3];
        uint4 w4 = wsv[4], w5 = wsv[5], w6 = wsv[6], w7 = wsv[7];

        __syncthreads();
        *(uint4*)&As[sm * 64 + ( sc      ^ swA)] = av0;
        *(uint4*)&As[sm * 64 + ((sc + 8) ^ swA)] = av1;
        {
            const int base = tid * 64;
            *(uint4*)&Bs[base + ( 0 ^ swB)] = w0;
            *(uint4*)&Bs[base + ( 8 ^ swB)] = w1;
            *(uint4*)&Bs[base + (16 ^ swB)] = w2;
            *(uint4*)&Bs[base + (24 ^ swB)] = w3;
            *(uint4*)&Bs[base + (32 ^ swB)] = w4;
            *(uint4*)&Bs[base + (40 ^ swB)] = w5;
            *(uint4*)&Bs[base + (48 ^ swB)] = w6;
            *(uint4*)&Bs[base + (56 ^ swB)] = w7;
        }
        __syncthreads();

        #pragma unroll
        for (int kh = 0; kh < 2; ++kh) {
            const int kb = kh * 32 + lh * 8;
            bf16x8 af[4], bfr[4];
            #pragma unroll
            for (int i = 0; i < 4; ++i) {
                int m = i * 16 + lr;
                af[i] = *(const bf16x8*)&As[m * 64 + (kb ^ ((m & 7) << 3))];
            }
            #pragma unroll
            for (int j = 0; j < 4; ++j) {
                int n = wave * 64 + j * 16 + lr;
                bfr[j] = *(const bf16x8*)&Bs[n * 64 + (kb ^ ((n & 7) << 3))];
            }
            #pragma unroll
            for (int i = 0; i < 4; ++i)
                #pragma unroll
                for (int j = 0; j < 4; ++j)
                    acc[i][j] = __builtin_amdgcn_mfma_f32_16x16x32_bf16(af[i], bfr[j], acc[i][j], 0, 0, 0);
        }
    }

    float bv[4];
    #pragma unroll
    for (int j = 0; j < 4; ++j) bv[j] = b1[wave * 64 + j * 16 + lr];
    #pragma unroll
    for (int i = 0; i < 4; ++i) {
        #pragma unroll
        for (int r = 0; r < 4; ++r) {
            int m = i * 16 + lh * 4 + r;
            int node = n0 + m;
            if (node < N_NODES) {
                float4 v;
                v.x = acc[i][0][r] + bv[0];
                v.y = acc[i][1][r] + bv[1];
                v.z = acc[i][2][r] + bv[2];
                v.w = acc[i][3][r] + bv[3];
                *(float4*)&xw1[(size_t)node * D + (size_t)(wave * 16 + lr) * 4] = v;
            }
        }
    }
}

// ---------------- edge GEMM (K=256) + in-register segmented aggregation ----------------
// R12 structure; epilogue-1 gathers are now single float4 loads (permuted xw1),
// epilogue-2 interior flag comes packed in snd (no rowptr loads on the scan path).
__global__ __launch_bounds__(256, 3) void k_edge_csr(
    const float* __restrict__ ea, const ushort_t* __restrict__ w1bt,
    const float* __restrict__ xw1, const int* __restrict__ elist,
    const int* __restrict__ rowg, const int* __restrict__ posnode,
    float* __restrict__ agg)
{
    __shared__ __align__(16) ushort_t As[2][64 * 64];  // 2 x 8KB, ea tiles (bf16)
    __shared__ int snd[64];                            // packed (node<<1)|interior
    const int tid = threadIdx.x;
    const int wave = tid >> 6, lane = tid & 63;
    const int lr = lane & 15, lh = lane >> 4;
    const int p0 = blockIdx.x * 64;

    if (tid < 64) {
        int p = p0 + tid;
        snd[tid] = (p < N_EDGES) ? posnode[min(p, N_EDGES - 1)] : -1;
    }

    const int sm = tid >> 2;           // A row staged by this thread
    const int sc = (tid & 3) << 4;     // 16-elem chunk within 64-elem K-step
    int ps = p0 + sm; if (ps >= N_EDGES) ps = N_EDGES - 1;
    const float* earow = ea + (size_t)elist[ps] * D;
    const int swA = (sm & 7) << 3;

    // B row pointers: col n = wave*64 + j*16 + lr, pre-offset by lane k-phase
    const ushort_t* pw[4];
    #pragma unroll
    for (int j = 0; j < 4; ++j)
        pw[j] = w1bt + (size_t)(wave * 64 + j * 16 + lr) * D + lh * 8;

    f32x4 acc[4][4];
    #pragma unroll
    for (int i = 0; i < 4; ++i)
        #pragma unroll
        for (int j = 0; j < 4; ++j)
            acc[i][j] = (f32x4){0.f, 0.f, 0.f, 0.f};

    // ---- prologue: stage step 0, prefetch step 1 ----
    float4 a0, a1, a2, a3;
    {
        const float4* s = (const float4*)(earow + sc);
        a0 = s[0]; a1 = s[1]; a2 = s[2]; a3 = s[3];
    }
    {
        uint4 av0, av1;
        av0.x = pk2(a0.x, a0.y); av0.y = pk2(a0.z, a0.w);
        av0.z = pk2(a1.x, a1.y); av0.w = pk2(a1.z, a1.w);
        av1.x = pk2(a2.x, a2.y); av1.y = pk2(a2.z, a2.w);
        av1.z = pk2(a3.x, a3.y); av1.w = pk2(a3.z, a3.w);
        *(uint4*)&As[0][sm * 64 + ( sc      ^ swA)] = av0;
        *(uint4*)&As[0][sm * 64 + ((sc + 8) ^ swA)] = av1;
    }
    {
        const float4* s = (const float4*)(earow + 64 + sc);
        a0 = s[0]; a1 = s[1]; a2 = s[2]; a3 = s[3];
    }
    barrier_nodrain();                 // snd + buf0 visible

    // ---- K-loop: 4 steps of 64, double-buffered, one non-draining barrier per step ----
    #pragma unroll
    for (int kk = 0; kk < 4; ++kk) {
        const int k0 = kk << 6;
        const ushort_t* cur = As[kk & 1];

        bf16x8 b0[4], b1[4];
        #pragma unroll
        for (int j = 0; j < 4; ++j) {
            b0[j] = *(const bf16x8*)(pw[j] + k0);
            b1[j] = *(const bf16x8*)(pw[j] + k0 + 32);
        }
        bf16x8 af0[4], af1[4];
        #pragma unroll
        for (int i = 0; i < 4; ++i) {
            const int m = i * 16 + lr;
            const int sw = (m & 7) << 3;
            af0[i] = *(const bf16x8*)&cur[m * 64 + (( lh * 8     ) ^ sw)];
            af1[i] = *(const bf16x8*)&cur[m * 64 + ((32 + lh * 8) ^ sw)];
        }
        #pragma unroll
        for (int i = 0; i < 4; ++i)
            #pragma unroll
            for (int j = 0; j < 4; ++j) {
                acc[i][j] = __builtin_amdgcn_mfma_f32_16x16x32_bf16(af0[i], b0[j], acc[i][j], 0, 0, 0);
                acc[i][j] = __builtin_amdgcn_mfma_f32_16x16x32_bf16(af1[i], b1[j], acc[i][j], 0, 0, 0);
            }

        if (kk < 3) {
            uint4 av0, av1;
            av0.x = pk2(a0.x, a0.y); av0.y = pk2(a0.z, a0.w);
            av0.z = pk2(a1.x, a1.y); av0.w = pk2(a1.z, a1.w);
            av1.x = pk2(a2.x, a2.y); av1.y = pk2(a2.z, a2.w);
            av1.z = pk2(a3.x, a3.y); av1.w = pk2(a3.z, a3.w);
            ushort_t* nxt = (ushort_t*)As[(kk + 1) & 1];
            *(uint4*)&nxt[sm * 64 + ( sc      ^ swA)] = av0;
            *(uint4*)&nxt[sm * 64 + ((sc + 8) ^ swA)] = av1;
            if (kk < 2) {
                const float4* s = (const float4*)(earow + ((kk + 2) << 6) + sc);
                a0 = s[0]; a1 = s[1]; a2 = s[2]; a3 = s[3];
            }
            barrier_nodrain();
        }
    }

    // ---- epilogue 1: add gathered xw1[src] (one float4 per (i,r)), relu ----
    #pragma unroll
    for (int i = 0; i < 4; ++i) {
        #pragma unroll
        for (int r = 0; r < 4; ++r) {
            const int m = i * 16 + lh * 4 + r;
            const bool ok = (p0 + m < N_EDGES);
            const int srw = rowg[min(p0 + m, N_EDGES - 1)];
            const float4 xv = *(const float4*)&xw1[(size_t)srw * D + (size_t)(wave * 16 + lr) * 4];
            const float xvv[4] = {xv.x, xv.y, xv.z, xv.w};
            #pragma unroll
            for (int j = 0; j < 4; ++j) {
                float v = acc[i][j][r] + xvv[j];
                v = v > 0.f ? v : 0.f;
                acc[i][j][r] = ok ? v : 0.f;
            }
        }
    }

    // ---- epilogue 2: block-uniform segment loop, in-register reduce (proven) ----
    int a = 0;
    while (a < 64) {
        const int raw = snd[a];
        int b = a + 1;
        while (b < 64 && snd[b] == raw) ++b;
        if (raw >= 0) {
            const int node = raw >> 1;
            const int interior = raw & 1;
            float s0 = 0.f, s1 = 0.f, s2 = 0.f, s3 = 0.f;
            #pragma unroll
            for (int i = 0; i < 4; ++i) {
                if (b <= i * 16 || a >= (i + 1) * 16) continue;  // uniform skip
                #pragma unroll
                for (int r = 0; r < 4; ++r) {
                    const int m = i * 16 + lh * 4 + r;
                    const bool in = (m >= a) && (m < b);
                    s0 += in ? acc[i][0][r] : 0.f;
                    s1 += in ? acc[i][1][r] : 0.f;
                    s2 += in ? acc[i][2][r] : 0.f;
                    s3 += in ? acc[i][3][r] : 0.f;
                }
            }
            // fold the 4 lh groups (lanes differ in bits 4,5)
            s0 += __shfl_xor(s0, 16, 64); s0 += __shfl_xor(s0, 32, 64);
            s1 += __shfl_xor(s1, 16, 64); s1 += __shfl_xor(s1, 32, 64);
            s2 += __shfl_xor(s2, 16, 64); s2 += __shfl_xor(s2, 32, 64);
            s3 += __shfl_xor(s3, 16, 64); s3 += __shfl_xor(s3, 32, 64);
            if (lh == 0) {
                float* dst = agg + (size_t)node * D + wave * 64 + lr;
                if (interior) {
                    dst[0]  = s0; dst[16] = s1; dst[32] = s2; dst[48] = s3;
                } else {
                    atomicAdd(&dst[0],  s0); atomicAdd(&dst[16], s1);
                    atomicAdd(&dst[32], s2); atomicAdd(&dst[48], s3);
                }
            }
        }
        a = b;
    }
}

// ---------------- node GEMM ----------------
// out[i][n] = relu( concat(x[i], agg[i]/max(cnt,1)) @ W2 + b2 )
__global__ __launch_bounds__(256) void k_node(
    const ushort_t* __restrict__ xb, const float* __restrict__ agg,
    const int* __restrict__ cnti,
    const ushort_t* __restrict__ w2t, const float* __restrict__ b2,
    float* __restrict__ out)
{
    __shared__ __align__(16) ushort_t As[64 * 64];
    __shared__ __align__(16) ushort_t Bs[256 * 64];
    const int tid = threadIdx.x;
    const int wave = tid >> 6, lane = tid & 63;
    const int lr = lane & 15, lh = lane >> 4;
    const int n0 = blockIdx.x * 64;

    const int sm = tid >> 2;
    const int sc = (tid & 3) << 4;
    int ns = n0 + sm; if (ns >= N_NODES) ns = N_NODES - 1;
    const ushort_t* xrow = xb + (size_t)ns * D;
    const float*    arow = agg + (size_t)ns * D;
    const float     ic   = 1.0f / fmaxf((float)cnti[ns], 1.0f);
    const ushort_t* wrow = w2t + (size_t)tid * TWO_D;
    const int swA = (sm & 7) << 3;
    const int swB = (tid & 7) << 3;

    f32x4 acc[4][4];
    #pragma unroll
    for (int i = 0; i < 4; ++i)
        #pragma unroll
        for (int j = 0; j < 4; ++j)
            acc[i][j] = (f32x4){0.f, 0.f, 0.f, 0.f};

    for (int kk = 0; kk < 8; ++kk) {
        const int k0 = kk << 6;
        uint4 av0, av1;
        if (kk < 4) {
            const uint4* s = (const uint4*)(xrow + k0 + sc);
            av0 = s[0]; av1 = s[1];
        } else {
            const float4* s = (const float4*)(arow + (k0 - D) + sc);
            float4 f0 = s[0], f1 = s[1], f2 = s[2], f3 = s[3];
            f0.x *= ic; f0.y *= ic; f0.z *= ic; f0.w *= ic;
            f1.x *= ic; f1.y *= ic; f1.z *= ic; f1.w *= ic;
            f2.x *= ic; f2.y *= ic; f2.z *= ic; f2.w *= ic;
            f3.x *= ic; f3.y *= ic; f3.z *= ic; f3.w *= ic;
            av0.x = pk2(f0.x, f0.y); av0.y = pk2(f0.z, f0.w);
            av0.z = pk2(f1.x, f1.y); av0.w = pk2(f1.z, f1.w);
            av1.x = pk2(f2.x, f2.y); av1.y = pk2(f2.z, f2.w);
            av1.z = pk2(f3.x, f3.y); av1.w = pk2(f3.z, f3.w);
        }
        const uint4* wsv = (const uint4*)(wrow + k0);
        uint4 w0 = wsv[0], w1 = wsv[1], w2 = wsv[2], w3 = wsv[3];
        uint4 w4 = wsv[4], w5 = wsv[5], w6 = wsv[6], w7 = wsv[7];

        barrier_nodrain();
        *(uint4*)&As[sm * 64 + ( sc      ^ swA)] = av0;
        *(uint4*)&As[sm * 64 + ((sc + 8) ^ swA)] = av1;
        {
            const int base = tid * 64;
            *(uint4*)&Bs[base + ( 0 ^ swB)] = w0;
            *(uint4*)&Bs[base + ( 8 ^ swB)] = w1;
            *(uint4*)&Bs[base + (16 ^ swB)] = w2;
            *(uint4*)&Bs[base + (24 ^ swB)] = w3;
            *(uint4*)&Bs[base + (32 ^ swB)] = w4;
            *(uint4*)&Bs[base + (40 ^ swB)] = w5;
            *(uint4*)&Bs[base + (48 ^ swB)] = w6;
            *(uint4*)&Bs[base + (56 ^ swB)] = w7;
        }
        barrier_nodrain();

        #pragma unroll
        for (int kh = 0; kh < 2; ++kh) {
            const int kb = kh * 32 + lh * 8;
            bf16x8 af[4], bfr[4];
            #pragma unroll
            for (int i = 0; i < 4; ++i) {
                int m = i * 16 + lr;
                af[i] = *(const bf16x8*)&As[m * 64 + (kb ^ ((m & 7) << 3))];
            }
            #pragma unroll
            for (int j = 0; j < 4; ++j) {
                int n = wave * 64 + j * 16 + lr;
                bfr[j] = *(const bf16x8*)&Bs[n * 64 + (kb ^ ((n & 7) << 3))];
            }
            #pragma unroll
            for (int i = 0; i < 4; ++i)
                #pragma unroll
                for (int j = 0; j < 4; ++j)
                    acc[i][j] = __builtin_amdgcn_mfma_f32_16x16x32_bf16(af[i], bfr[j], acc[i][j], 0, 0, 0);
        }
    }

    float bv[4];
    #pragma unroll
    for (int j = 0; j < 4; ++j) bv[j] = b2[wave * 64 + j * 16 + lr];
    #pragma unroll
    for (int i = 0; i < 4; ++i) {
        #pragma unroll
        for (int r = 0; r < 4; ++r) {
            int m = i * 16 + lh * 4 + r;
            int node = n0 + m;
            if (node < N_NODES) {
                float* orow = out + (size_t)node * D;
                #pragma unroll
                for (int j = 0; j < 4; ++j) {
                    float v = acc[i][j][r] + bv[j];
                    orow[wave * 64 + j * 16 + lr] = v > 0.f ? v : 0.f;
                }
            }
        }
    }
}

// ---------------- launch ----------------

extern "C" void kernel_launch(void* const* d_in, const int* in_sizes, int n_in,
                              void* d_out, int out_size, void* d_ws, size_t ws_size,
                              hipStream_t stream)
{
    const float* x  = (const float*)d_in[0];
    const int*   ei = (const int*)d_in[1];      // [2*E] int32: rows then cols
    const float* ea = (const float*)d_in[2];
    const float* W1 = (const float*)d_in[5];
    const float* b1 = (const float*)d_in[6];
    const float* W2 = (const float*)d_in[7];
    const float* b2 = (const float*)d_in[8];
    float* out = (float*)d_out;

    const int* rowi = ei;
    const int* coli = ei + N_EDGES;
    char* ws = (char*)d_ws;

    size_t off = 0;
    auto take = [&](size_t bytes) {
        char* p = ws + off;
        off = (off + bytes + 255) & ~(size_t)255;
        return p;
    };

    ushort_t* xb      = (ushort_t*)take((size_t)N_NODES * D * 2);
    ushort_t* w1at    = (ushort_t*)take((size_t)D * D * 2);
    ushort_t* w1bt    = (ushort_t*)take((size_t)D * D * 2);
    ushort_t* w2t     = (ushort_t*)take((size_t)D * TWO_D * 2);
    float*    xw1     = (float*)take((size_t)N_NODES * D * 4);
    float*    agg     = (float*)take((size_t)N_NODES * D * 4);
    int*      cnti    = (int*)take(50016 * 4);
    int*      rowptr  = (int*)take(50016 * 4);
    int*      cursor  = (int*)take(50016 * 4);
    int*      bsum    = (int*)take(256 * 4);
    int*      elist   = (int*)take((size_t)N_EDGES * 4);
    int*      rowg    = (int*)take((size_t)N_EDGES * 4);
    int*      posnode = (int*)take((size_t)N_EDGES * 4);

    const int NB = (N_NODES + 255) / 256;          // 196
    const int EB = (N_EDGES + 255) / 256;          // 1954
    const int NGB = (N_NODES + 63) / 64;           // 782
    const int EGB = (N_EDGES + 63) / 64;           // 7813

    k_cvt_x<<<(N_NODES * D / 8 + 255) / 256, 256, 0, stream>>>(x, xb, N_NODES * D / 8);
    k_wt   <<<D, 256, 0, stream>>>(W1, w1at, D);
    k_wt   <<<D, 256, 0, stream>>>(W1 + (size_t)D * D, w1bt, D);
    k_wt   <<<D, 256, 0, stream>>>(W2, w2t, TWO_D);

    k_zero   <<<49, 256, 0, stream>>>((float*)cnti, 50016 / 4);
    k_count_i<<<EB, 256, 0, stream>>>(coli, cnti);
    k_scan_a <<<NB, 256, 0, stream>>>(cnti, rowptr, bsum);
    k_scan_b <<<1, 256, 0, stream>>>(bsum, NB);
    k_scan_c <<<NB, 256, 0, stream>>>(rowptr, bsum, cursor);
    k_fill   <<<EB, 256, 0, stream>>>(coli, rowi, cursor, elist, rowg);
    k_posnode<<<EB, 256, 0, stream>>>(rowptr, posnode);

    k_xw1    <<<NGB, 256, 0, stream>>>(xb, w1at, b1, xw1);
    k_zero   <<<(N_NODES * D / 4 + 255) / 256, 256, 0, stream>>>(agg, N_NODES * D / 4);
    k_edge_csr<<<EGB, 256, 0, stream>>>(ea, w1bt, xw1, elist, rowg, posnode, agg);
    k_node   <<<NGB, 256, 0, stream>>>(xb, agg, cnti, w2t, b2, out);
}

// Round 14
// 462.522 us; speedup vs baseline: 1.1296x; 1.0074x over previous
//
#include <hip/hip_runtime.h>

#define N_NODES 50000
#define N_EDGES 500000
#define D 256
#define TWO_D 512

typedef __attribute__((ext_vector_type(8))) __bf16 bf16x8;
typedef __attribute__((ext_vector_type(4))) float f32x4;
typedef unsigned short ushort_t;

__device__ __forceinline__ unsigned short f2bf(float f) {
    unsigned int u = __builtin_bit_cast(unsigned int, f);
    u += 0x7FFFu + ((u >> 16) & 1u);   // round-to-nearest-even
    return (unsigned short)(u >> 16);
}
__device__ __forceinline__ unsigned int pk2(float lo, float hi) {
    return (unsigned int)f2bf(lo) | ((unsigned int)f2bf(hi) << 16);
}

// Non-draining workgroup barrier (orders LDS, does not drain vmcnt).
__device__ __forceinline__ void barrier_nodrain() {
    asm volatile("s_waitcnt lgkmcnt(0)" ::: "memory");
    __builtin_amdgcn_s_barrier();
    __builtin_amdgcn_sched_barrier(0);
}

// ---------------- prep kernels ----------------

__global__ void k_zero(float* __restrict__ p, int n4) {
    int i = blockIdx.x * blockDim.x + threadIdx.x;
    if (i < n4) ((float4*)p)[i] = make_float4(0.f, 0.f, 0.f, 0.f);
}

__global__ void k_cvt_x(const float* __restrict__ x, ushort_t* __restrict__ xb, int n8) {
    int i = blockIdx.x * blockDim.x + threadIdx.x;
    if (i < n8) {
        const float4* s = (const float4*)(x + (size_t)i * 8);
        float4 a = s[0], b = s[1];
        uint4 o;
        o.x = pk2(a.x, a.y); o.y = pk2(a.z, a.w);
        o.z = pk2(b.x, b.y); o.w = pk2(b.z, b.w);
        *(uint4*)(xb + (size_t)i * 8) = o;
    }
}

// W slice [KW rows of D cols] f32 -> Wt [D][KW] bf16 (transposed)
__global__ void k_wt(const float* __restrict__ w, ushort_t* __restrict__ wt, int KW) {
    int n = blockIdx.x;
    for (int k = threadIdx.x; k < KW; k += blockDim.x)
        wt[(size_t)n * KW + k] = f2bf(w[(size_t)k * D + n]);
}

__global__ void k_count_i(const int* __restrict__ coli, int* __restrict__ cnt) {
    int e = blockIdx.x * blockDim.x + threadIdx.x;
    if (e < N_EDGES) atomicAdd(&cnt[coli[e]], 1);
}

// ---------------- CSR build ----------------

__device__ __forceinline__ int iscan_block(int v, int tid) {
    int lane = tid & 63, wv = tid >> 6;
    int s = v;
    #pragma unroll
    for (int off = 1; off < 64; off <<= 1) {
        int t = __shfl_up(s, off, 64);
        if (lane >= off) s += t;
    }
    __shared__ int wsum[4];
    if (lane == 63) wsum[wv] = s;
    __syncthreads();
    #pragma unroll
    for (int w = 0; w < 3; ++w)
        if (wv > w) s += wsum[w];
    return s;
}

__global__ void k_scan_a(const int* __restrict__ cnt, int* __restrict__ rowptr,
                         int* __restrict__ bsum) {
    int i = blockIdx.x * 256 + threadIdx.x;
    int v = (i < N_NODES) ? cnt[i] : 0;
    int s = iscan_block(v, threadIdx.x);
    if (i < N_NODES) rowptr[i] = s - v;
    if (threadIdx.x == 255) bsum[blockIdx.x] = s;
}

__global__ void k_scan_b(int* __restrict__ bsum, int nb) {
    int i = threadIdx.x;
    int v = (i < nb) ? bsum[i] : 0;
    int s = iscan_block(v, i);
    if (i < nb) bsum[i] = s - v;
}

__global__ void k_scan_c(int* __restrict__ rowptr, const int* __restrict__ bsum,
                         int* __restrict__ cursor) {
    int i = blockIdx.x * 256 + threadIdx.x;
    if (i < N_NODES) {
        int r = rowptr[i] + bsum[blockIdx.x];
        rowptr[i] = r;
        cursor[i] = r;
    }
    if (i == 0) rowptr[N_NODES] = N_EDGES;
}

__global__ void k_fill(const int* __restrict__ coli, const int* __restrict__ rowi,
                       int* __restrict__ cursor, int* __restrict__ elist,
                       int* __restrict__ rowg) {
    int e = blockIdx.x * blockDim.x + threadIdx.x;
    if (e < N_EDGES) {
        int p = atomicAdd(&cursor[coli[e]], 1);
        elist[p] = e;
        rowg[p] = rowi[e];
    }
}

// CSR position -> packed (node<<1)|interior
__global__ void k_posnode(const int* __restrict__ rowptr, int* __restrict__ posnode) {
    int p = blockIdx.x * blockDim.x + threadIdx.x;
    if (p >= N_EDGES) return;
    int lo = 0, hi = N_NODES;
    while (hi - lo > 1) {
        int mid = (lo + hi) >> 1;
        if (rowptr[mid] <= p) lo = mid; else hi = mid;
    }
    const int t0 = p & ~63;
    const int inter = (rowptr[lo] >= t0) && (rowptr[lo + 1] <= t0 + 64);
    posnode[p] = (lo << 1) | inter;
}

// ---------------- xw1 = x @ W1a + b1 (f32, fragment-permuted layout) ----------------
__global__ __launch_bounds__(256) void k_xw1(
    const ushort_t* __restrict__ xb, const ushort_t* __restrict__ w1at,
    const float* __restrict__ b1, float* __restrict__ xw1)
{
    __shared__ __align__(16) ushort_t As[64 * 64];
    __shared__ __align__(16) ushort_t Bs[256 * 64];
    const int tid = threadIdx.x;
    const int wave = tid >> 6, lane = tid & 63;
    const int lr = lane & 15, lh = lane >> 4;
    const int n0 = blockIdx.x * 64;

    const int sm = tid >> 2;
    const int sc = (tid & 3) << 4;
    int ns = n0 + sm; if (ns >= N_NODES) ns = N_NODES - 1;
    const ushort_t* xrow = xb + (size_t)ns * D;
    const ushort_t* wrow = w1at + (size_t)tid * D;
    const int swA = (sm & 7) << 3;
    const int swB = (tid & 7) << 3;

    f32x4 acc[4][4];
    #pragma unroll
    for (int i = 0; i < 4; ++i)
        #pragma unroll
        for (int j = 0; j < 4; ++j)
            acc[i][j] = (f32x4){0.f, 0.f, 0.f, 0.f};

    for (int kk = 0; kk < 4; ++kk) {
        const int k0 = kk << 6;
        const uint4* sx = (const uint4*)(xrow + k0 + sc);
        uint4 av0 = sx[0], av1 = sx[1];
        const uint4* wsv = (const uint4*)(wrow + k0);
        uint4 w0 = wsv[0], w1 = wsv[1], w2 = wsv[2], w3 = wsv[3];
        uint4 w4 = wsv[4], w5 = wsv[5], w6 = wsv[6], w7 = wsv[7];

        __syncthreads();
        *(uint4*)&As[sm * 64 + ( sc      ^ swA)] = av0;
        *(uint4*)&As[sm * 64 + ((sc + 8) ^ swA)] = av1;
        {
            const int base = tid * 64;
            *(uint4*)&Bs[base + ( 0 ^ swB)] = w0;
            *(uint4*)&Bs[base + ( 8 ^ swB)] = w1;
            *(uint4*)&Bs[base + (16 ^ swB)] = w2;
            *(uint4*)&Bs[base + (24 ^ swB)] = w3;
            *(uint4*)&Bs[base + (32 ^ swB)] = w4;
            *(uint4*)&Bs[base + (40 ^ swB)] = w5;
            *(uint4*)&Bs[base + (48 ^ swB)] = w6;
            *(uint4*)&Bs[base + (56 ^ swB)] = w7;
        }
        __syncthreads();

        #pragma unroll
        for (int kh = 0; kh < 2; ++kh) {
            const int kb = kh * 32 + lh * 8;
            bf16x8 af[4], bfr[4];
            #pragma unroll
            for (int i = 0; i < 4; ++i) {
                int m = i * 16 + lr;
                af[i] = *(const bf16x8*)&As[m * 64 + (kb ^ ((m & 7) << 3))];
            }
            #pragma unroll
            for (int j = 0; j < 4; ++j) {
                int n = wave * 64 + j * 16 + lr;
                bfr[j] = *(const bf16x8*)&Bs[n * 64 + (kb ^ ((n & 7) << 3))];
            }
            #pragma unroll
            for (int i = 0; i < 4; ++i)
                #pragma unroll
                for (int j = 0; j < 4; ++j)
                    acc[i][j] = __builtin_amdgcn_mfma_f32_16x16x32_bf16(af[i], bfr[j], acc[i][j], 0, 0, 0);
        }
    }

    float bv[4];
    #pragma unroll
    for (int j = 0; j < 4; ++j) bv[j] = b1[wave * 64 + j * 16 + lr];
    #pragma unroll
    for (int i = 0; i < 4; ++i) {
        #pragma unroll
        for (int r = 0; r < 4; ++r) {
            int m = i * 16 + lh * 4 + r;
            int node = n0 + m;
            if (node < N_NODES) {
                float4 v;
                v.x = acc[i][0][r] + bv[0];
                v.y = acc[i][1][r] + bv[1];
                v.z = acc[i][2][r] + bv[2];
                v.w = acc[i][3][r] + bv[3];
                *(float4*)&xw1[(size_t)node * D + (size_t)(wave * 16 + lr) * 4] = v;
            }
        }
    }
}

// ---------------- edge GEMM (K=256) + in-register segmented aggregation ----------------
// R13 semantics; VMEM FIFO restructured so the load queue NEVER drains mid-loop:
//  - ea staging regs ping-pong (st[2][4]): next-next ea issued at step TOP, before
//    the dependent LDS write, so the write's wait is counted vmcnt leaving them in flight.
//  - B prefetched one step ahead (bReg), issued AFTER this step's MFMA consumed it,
//    so MFMA's wait for B forces only the already-flown ea(k+1), never ea(k+2).
__global__ __launch_bounds__(256, 3) void k_edge_csr(
    const float* __restrict__ ea, const ushort_t* __restrict__ w1bt,
    const float* __restrict__ xw1, const int* __restrict__ elist,
    const int* __restrict__ rowg, const int* __restrict__ posnode,
    float* __restrict__ agg)
{
    __shared__ __align__(16) ushort_t As[2][64 * 64];  // 2 x 8KB, ea tiles (bf16)
    __shared__ int snd[64];                            // packed (node<<1)|interior
    const int tid = threadIdx.x;
    const int wave = tid >> 6, lane = tid & 63;
    const int lr = lane & 15, lh = lane >> 4;
    const int p0 = blockIdx.x * 64;

    if (tid < 64) {
        int p = p0 + tid;
        snd[tid] = (p < N_EDGES) ? posnode[min(p, N_EDGES - 1)] : -1;
    }

    const int sm = tid >> 2;           // A row staged by this thread
    const int sc = (tid & 3) << 4;     // 16-elem chunk within 64-elem K-step
    int ps = p0 + sm; if (ps >= N_EDGES) ps = N_EDGES - 1;
    const float* earow = ea + (size_t)elist[ps] * D;
    const int swA = (sm & 7) << 3;

    // B row pointers: col n = wave*64 + j*16 + lr, pre-offset by lane k-phase
    const ushort_t* pw[4];
    #pragma unroll
    for (int j = 0; j < 4; ++j)
        pw[j] = w1bt + (size_t)(wave * 64 + j * 16 + lr) * D + lh * 8;

    f32x4 acc[4][4];
    #pragma unroll
    for (int i = 0; i < 4; ++i)
        #pragma unroll
        for (int j = 0; j < 4; ++j)
            acc[i][j] = (f32x4){0.f, 0.f, 0.f, 0.f};

    float4 st[2][4];      // ea staging ping-pong (static indexing: loop fully unrolled)
    bf16x8 bReg[8];       // B for current step (prefetched one step ahead)

    // ---- prologue: issue ea0, ea1, B0; write step0; barrier ----
    {
        const float4* s = (const float4*)(earow + sc);
        st[0][0] = s[0]; st[0][1] = s[1]; st[0][2] = s[2]; st[0][3] = s[3];
    }
    {
        const float4* s = (const float4*)(earow + 64 + sc);
        st[1][0] = s[0]; st[1][1] = s[1]; st[1][2] = s[2]; st[1][3] = s[3];
    }
    #pragma unroll
    for (int j = 0; j < 4; ++j) {
        bReg[j]     = *(const bf16x8*)(pw[j]);
        bReg[4 + j] = *(const bf16x8*)(pw[j] + 32);
    }
    {
        // waits only for ea0 (oldest); ea1 + B0 stay in flight
        uint4 av0, av1;
        av0.x = pk2(st[0][0].x, st[0][0].y); av0.y = pk2(st[0][0].z, st[0][0].w);
        av0.z = pk2(st[0][1].x, st[0][1].y); av0.w = pk2(st[0][1].z, st[0][1].w);
        av1.x = pk2(st[0][2].x, st[0][2].y); av1.y = pk2(st[0][2].z, st[0][2].w);
        av1.z = pk2(st[0][3].x, st[0][3].y); av1.w = pk2(st[0][3].z, st[0][3].w);
        *(uint4*)&As[0][sm * 64 + ( sc      ^ swA)] = av0;
        *(uint4*)&As[0][sm * 64 + ((sc + 8) ^ swA)] = av1;
    }
    barrier_nodrain();

    // ---- K-loop: 4 steps of 64 ----
    #pragma unroll
    for (int kk = 0; kk < 4; ++kk) {
        // (1) issue ea for step kk+2 into the just-freed staging set (youngest in FIFO)
        if (kk < 2) {
            const float4* s = (const float4*)(earow + ((kk + 2) << 6) + sc);
            st[kk & 1][0] = s[0]; st[kk & 1][1] = s[1];
            st[kk & 1][2] = s[2]; st[kk & 1][3] = s[3];
        }

        // (2) LDS reads for this step
        const ushort_t* cur = As[kk & 1];
        bf16x8 af0[4], af1[4];
        #pragma unroll
        for (int i = 0; i < 4; ++i) {
            const int m = i * 16 + lr;
            const int sw = (m & 7) << 3;
            af0[i] = *(const bf16x8*)&cur[m * 64 + (( lh * 8     ) ^ sw)];
            af1[i] = *(const bf16x8*)&cur[m * 64 + ((32 + lh * 8) ^ sw)];
        }

        // (3) MFMA with prefetched B (waiting for it retires at most ea[kk+1], never ea[kk+2])
        #pragma unroll
        for (int i = 0; i < 4; ++i)
            #pragma unroll
            for (int j = 0; j < 4; ++j) {
                acc[i][j] = __builtin_amdgcn_mfma_f32_16x16x32_bf16(af0[i], bReg[j],     acc[i][j], 0, 0, 0);
                acc[i][j] = __builtin_amdgcn_mfma_f32_16x16x32_bf16(af1[i], bReg[4 + j], acc[i][j], 0, 0, 0);
            }

        if (kk < 3) {
            // (4) issue B for step kk+1 (bReg consumed by MFMA above)
            const int kn = (kk + 1) << 6;
            #pragma unroll
            for (int j = 0; j < 4; ++j) {
                bReg[j]     = *(const bf16x8*)(pw[j] + kn);
                bReg[4 + j] = *(const bf16x8*)(pw[j] + kn + 32);
            }
            // (5) write step kk+1 staging regs to the other LDS buffer
            //     (ea[kk+1] already retired by MFMA's wait; B[kk+1]+ea[kk+2] keep flying)
            uint4 av0, av1;
            const int sB = (kk + 1) & 1;
            av0.x = pk2(st[sB][0].x, st[sB][0].y); av0.y = pk2(st[sB][0].z, st[sB][0].w);
            av0.z = pk2(st[sB][1].x, st[sB][1].y); av0.w = pk2(st[sB][1].z, st[sB][1].w);
            av1.x = pk2(st[sB][2].x, st[sB][2].y); av1.y = pk2(st[sB][2].z, st[sB][2].w);
            av1.z = pk2(st[sB][3].x, st[sB][3].y); av1.w = pk2(st[sB][3].z, st[sB][3].w);
            ushort_t* nxt = (ushort_t*)As[sB];
            *(uint4*)&nxt[sm * 64 + ( sc      ^ swA)] = av0;
            *(uint4*)&nxt[sm * 64 + ((sc + 8) ^ swA)] = av1;
            // (6) barrier (non-draining)
            barrier_nodrain();
        }
    }

    // ---- epilogue 1: add gathered xw1[src] (one float4 per (i,r)), relu ----
    #pragma unroll
    for (int i = 0; i < 4; ++i) {
        #pragma unroll
        for (int r = 0; r < 4; ++r) {
            const int m = i * 16 + lh * 4 + r;
            const bool ok = (p0 + m < N_EDGES);
            const int srw = rowg[min(p0 + m, N_EDGES - 1)];
            const float4 xv = *(const float4*)&xw1[(size_t)srw * D + (size_t)(wave * 16 + lr) * 4];
            const float xvv[4] = {xv.x, xv.y, xv.z, xv.w};
            #pragma unroll
            for (int j = 0; j < 4; ++j) {
                float v = acc[i][j][r] + xvv[j];
                v = v > 0.f ? v : 0.f;
                acc[i][j][r] = ok ? v : 0.f;
            }
        }
    }

    // ---- epilogue 2: block-uniform segment loop, in-register reduce (proven) ----
    int a = 0;
    while (a < 64) {
        const int raw = snd[a];
        int b = a + 1;
        while (b < 64 && snd[b] == raw) ++b;
        if (raw >= 0) {
            const int node = raw >> 1;
            const int interior = raw & 1;
            float s0 = 0.f, s1 = 0.f, s2 = 0.f, s3 = 0.f;
            #pragma unroll
            for (int i = 0; i < 4; ++i) {
                if (b <= i * 16 || a >= (i + 1) * 16) continue;  // uniform skip
                #pragma unroll
                for (int r = 0; r < 4; ++r) {
                    const int m = i * 16 + lh * 4 + r;
                    const bool in = (m >= a) && (m < b);
                    s0 += in ? acc[i][0][r] : 0.f;
                    s1 += in ? acc[i][1][r] : 0.f;
                    s2 += in ? acc[i][2][r] : 0.f;
                    s3 += in ? acc[i][3][r] : 0.f;
                }
            }
            // fold the 4 lh groups (lanes differ in bits 4,5)
            s0 += __shfl_xor(s0, 16, 64); s0 += __shfl_xor(s0, 32, 64);
            s1 += __shfl_xor(s1, 16, 64); s1 += __shfl_xor(s1, 32, 64);
            s2 += __shfl_xor(s2, 16, 64); s2 += __shfl_xor(s2, 32, 64);
            s3 += __shfl_xor(s3, 16, 64); s3 += __shfl_xor(s3, 32, 64);
            if (lh == 0) {
                float* dst = agg + (size_t)node * D + wave * 64 + lr;
                if (interior) {
                    dst[0]  = s0; dst[16] = s1; dst[32] = s2; dst[48] = s3;
                } else {
                    atomicAdd(&dst[0],  s0); atomicAdd(&dst[16], s1);
                    atomicAdd(&dst[32], s2); atomicAdd(&dst[48], s3);
                }
            }
        }
        a = b;
    }
}

// ---------------- node GEMM ----------------
// out[i][n] = relu( concat(x[i], agg[i]/max(cnt,1)) @ W2 + b2 )
__global__ __launch_bounds__(256) void k_node(
    const ushort_t* __restrict__ xb, const float* __restrict__ agg,
    const int* __restrict__ cnti,
    const ushort_t* __restrict__ w2t, const float* __restrict__ b2,
    float* __restrict__ out)
{
    __shared__ __align__(16) ushort_t As[64 * 64];
    __shared__ __align__(16) ushort_t Bs[256 * 64];
    const int tid = threadIdx.x;
    const int wave = tid >> 6, lane = tid & 63;
    const int lr = lane & 15, lh = lane >> 4;
    const int n0 = blockIdx.x * 64;

    const int sm = tid >> 2;
    const int sc = (tid & 3) << 4;
    int ns = n0 + sm; if (ns >= N_NODES) ns = N_NODES - 1;
    const ushort_t* xrow = xb + (size_t)ns * D;
    const float*    arow = agg + (size_t)ns * D;
    const float     ic   = 1.0f / fmaxf((float)cnti[ns], 1.0f);
    const ushort_t* wrow = w2t + (size_t)tid * TWO_D;
    const int swA = (sm & 7) << 3;
    const int swB = (tid & 7) << 3;

    f32x4 acc[4][4];
    #pragma unroll
    for (int i = 0; i < 4; ++i)
        #pragma unroll
        for (int j = 0; j < 4; ++j)
            acc[i][j] = (f32x4){0.f, 0.f, 0.f, 0.f};

    for (int kk = 0; kk < 8; ++kk) {
        const int k0 = kk << 6;
        uint4 av0, av1;
        if (kk < 4) {
            const uint4* s = (const uint4*)(xrow + k0 + sc);
            av0 = s[0]; av1 = s[1];
        } else {
            const float4* s = (const float4*)(arow + (k0 - D) + sc);
            float4 f0 = s[0], f1 = s[1], f2 = s[2], f3 = s[3];
            f0.x *= ic; f0.y *= ic; f0.z *= ic; f0.w *= ic;
            f1.x *= ic; f1.y *= ic; f1.z *= ic; f1.w *= ic;
            f2.x *= ic; f2.y *= ic; f2.z *= ic; f2.w *= ic;
            f3.x *= ic; f3.y *= ic; f3.z *= ic; f3.w *= ic;
            av0.x = pk2(f0.x, f0.y); av0.y = pk2(f0.z, f0.w);
            av0.z = pk2(f1.x, f1.y); av0.w = pk2(f1.z, f1.w);
            av1.x = pk2(f2.x, f2.y); av1.y = pk2(f2.z, f2.w);
            av1.z = pk2(f3.x, f3.y); av1.w = pk2(f3.z, f3.w);
        }
        const uint4* wsv = (const uint4*)(wrow + k0);
        uint4 w0 = wsv[0], w1 = wsv[1], w2 = wsv[2], w3 = wsv[3];
        uint4 w4 = wsv[4], w5 = wsv[5], w6 = wsv[6], w7 = wsv[7];

        barrier_nodrain();
        *(uint4*)&As[sm * 64 + ( sc      ^ swA)] = av0;
        *(uint4*)&As[sm * 64 + ((sc + 8) ^ swA)] = av1;
        {
            const int base = tid * 64;
            *(uint4*)&Bs[base + ( 0 ^ swB)] = w0;
            *(uint4*)&Bs[base + ( 8 ^ swB)] = w1;
            *(uint4*)&Bs[base + (16 ^ swB)] = w2;
            *(uint4*)&Bs[base + (24 ^ swB)] = w3;
            *(uint4*)&Bs[base + (32 ^ swB)] = w4;
            *(uint4*)&Bs[base + (40 ^ swB)] = w5;
            *(uint4*)&Bs[base + (48 ^ swB)] = w6;
            *(uint4*)&Bs[base + (56 ^ swB)] = w7;
        }
        barrier_nodrain();

        #pragma unroll
        for (int kh = 0; kh < 2; ++kh) {
            const int kb = kh * 32 + lh * 8;
            bf16x8 af[4], bfr[4];
            #pragma unroll
            for (int i = 0; i < 4; ++i) {
                int m = i * 16 + lr;
                af[i] = *(const bf16x8*)&As[m * 64 + (kb ^ ((m & 7) << 3))];
            }
            #pragma unroll
            for (int j = 0; j < 4; ++j) {
                int n = wave * 64 + j * 16 + lr;
                bfr[j] = *(const bf16x8*)&Bs[n * 64 + (kb ^ ((n & 7) << 3))];
            }
            #pragma unroll
            for (int i = 0; i < 4; ++i)
                #pragma unroll
                for (int j = 0; j < 4; ++j)
                    acc[i][j] = __builtin_amdgcn_mfma_f32_16x16x32_bf16(af[i], bfr[j], acc[i][j], 0, 0, 0);
        }
    }

    float bv[4];
    #pragma unroll
    for (int j = 0; j < 4; ++j) bv[j] = b2[wave * 64 + j * 16 + lr];
    #pragma unroll
    for (int i = 0; i < 4; ++i) {
        #pragma unroll
        for (int r = 0; r < 4; ++r) {
            int m = i * 16 + lh * 4 + r;
            int node = n0 + m;
            if (node < N_NODES) {
                float* orow = out + (size_t)node * D;
                #pragma unroll
                for (int j = 0; j < 4; ++j) {
                    float v = acc[i][j][r] + bv[j];
                    orow[wave * 64 + j * 16 + lr] = v > 0.f ? v : 0.f;
                }
            }
        }
    }
}

// ---------------- launch ----------------

extern "C" void kernel_launch(void* const* d_in, const int* in_sizes, int n_in,
                              void* d_out, int out_size, void* d_ws, size_t ws_size,
                              hipStream_t stream)
{
    const float* x  = (const float*)d_in[0];
    const int*   ei = (const int*)d_in[1];      // [2*E] int32: rows then cols
    const float* ea = (const float*)d_in[2];
    const float* W1 = (const float*)d_in[5];
    const float* b1 = (const float*)d_in[6];
    const float* W2 = (const float*)d_in[7];
    const float* b2 = (const float*)d_in[8];
    float* out = (float*)d_out;

    const int* rowi = ei;
    const int* coli = ei + N_EDGES;
    char* ws = (char*)d_ws;

    size_t off = 0;
    auto take = [&](size_t bytes) {
        char* p = ws + off;
        off = (off + bytes + 255) & ~(size_t)255;
        return p;
    };

    ushort_t* xb      = (ushort_t*)take((size_t)N_NODES * D * 2);
    ushort_t* w1at    = (ushort_t*)take((size_t)D * D * 2);
    ushort_t* w1bt    = (ushort_t*)take((size_t)D * D * 2);
    ushort_t* w2t     = (ushort_t*)take((size_t)D * TWO_D * 2);
    float*    xw1     = (float*)take((size_t)N_NODES * D * 4);
    float*    agg     = (float*)take((size_t)N_NODES * D * 4);
    int*      cnti    = (int*)take(50016 * 4);
    int*      rowptr  = (int*)take(50016 * 4);
    int*      cursor  = (int*)take(50016 * 4);
    int*      bsum    = (int*)take(256 * 4);
    int*      elist   = (int*)take((size_t)N_EDGES * 4);
    int*      rowg    = (int*)take((size_t)N_EDGES * 4);
    int*      posnode = (int*)take((size_t)N_EDGES * 4);

    const int NB = (N_NODES + 255) / 256;          // 196
    const int EB = (N_EDGES + 255) / 256;          // 1954
    const int NGB = (N_NODES + 63) / 64;           // 782
    const int EGB = (N_EDGES + 63) / 64;           // 7813

    k_cvt_x<<<(N_NODES * D / 8 + 255) / 256, 256, 0, stream>>>(x, xb, N_NODES * D / 8);
    k_wt   <<<D, 256, 0, stream>>>(W1, w1at, D);
    k_wt   <<<D, 256, 0, stream>>>(W1 + (size_t)D * D, w1bt, D);
    k_wt   <<<D, 256, 0, stream>>>(W2, w2t, TWO_D);

    k_zero   <<<49, 256, 0, stream>>>((float*)cnti, 50016 / 4);
    k_count_i<<<EB, 256, 0, stream>>>(coli, cnti);
    k_scan_a <<<NB, 256, 0, stream>>>(cnti, rowptr, bsum);
    k_scan_b <<<1, 256, 0, stream>>>(bsum, NB);
    k_scan_c <<<NB, 256, 0, stream>>>(rowptr, bsum, cursor);
    k_fill   <<<EB, 256, 0, stream>>>(coli, rowi, cursor, elist, rowg);
    k_posnode<<<EB, 256, 0, stream>>>(rowptr, posnode);

    k_xw1    <<<NGB, 256, 0, stream>>>(xb, w1at, b1, xw1);
    k_zero   <<<(N_NODES * D / 4 + 255) / 256, 256, 0, stream>>>(agg, N_NODES * D / 4);
    k_edge_csr<<<EGB, 256, 0, stream>>>(ea, w1bt, xw1, elist, rowg, posnode, agg);
    k_node   <<<NGB, 256, 0, stream>>>(xb, agg, cnti, w2t, b2, out);
}

// Round 15
// 461.403 us; speedup vs baseline: 1.1323x; 1.0024x over previous
//
#include <hip/hip_runtime.h>

#define N_NODES 50000
#define N_EDGES 500000
#define D 256
#define TWO_D 512

typedef __attribute__((ext_vector_type(8))) __bf16 bf16x8;
typedef __attribute__((ext_vector_type(4))) float f32x4;
typedef unsigned short ushort_t;

__device__ __forceinline__ unsigned short f2bf(float f) {
    unsigned int u = __builtin_bit_cast(unsigned int, f);
    u += 0x7FFFu + ((u >> 16) & 1u);   // round-to-nearest-even
    return (unsigned short)(u >> 16);
}
__device__ __forceinline__ unsigned int pk2(float lo, float hi) {
    return (unsigned int)f2bf(lo) | ((unsigned int)f2bf(hi) << 16);
}

// Non-draining workgroup barrier (orders LDS, does not drain vmcnt).
__device__ __forceinline__ void barrier_nodrain() {
    asm volatile("s_waitcnt lgkmcnt(0)" ::: "memory");
    __builtin_amdgcn_s_barrier();
    __builtin_amdgcn_sched_barrier(0);
}

// ---------------- prep kernels ----------------

__global__ void k_zero(float* __restrict__ p, int n4) {
    int i = blockIdx.x * blockDim.x + threadIdx.x;
    if (i < n4) ((float4*)p)[i] = make_float4(0.f, 0.f, 0.f, 0.f);
}

__global__ void k_cvt_x(const float* __restrict__ x, ushort_t* __restrict__ xb, int n8) {
    int i = blockIdx.x * blockDim.x + threadIdx.x;
    if (i < n8) {
        const float4* s = (const float4*)(x + (size_t)i * 8);
        float4 a = s[0], b = s[1];
        uint4 o;
        o.x = pk2(a.x, a.y); o.y = pk2(a.z, a.w);
        o.z = pk2(b.x, b.y); o.w = pk2(b.z, b.w);
        *(uint4*)(xb + (size_t)i * 8) = o;
    }
}

// W slice [KW rows of D cols] f32 -> Wt [D][KW] bf16 (transposed)
__global__ void k_wt(const float* __restrict__ w, ushort_t* __restrict__ wt, int KW) {
    int n = blockIdx.x;
    for (int k = threadIdx.x; k < KW; k += blockDim.x)
        wt[(size_t)n * KW + k] = f2bf(w[(size_t)k * D + n]);
}

__global__ void k_count_i(const int* __restrict__ coli, int* __restrict__ cnt) {
    int e = blockIdx.x * blockDim.x + threadIdx.x;
    if (e < N_EDGES) atomicAdd(&cnt[coli[e]], 1);
}

// ---------------- CSR build ----------------

__device__ __forceinline__ int iscan_block(int v, int tid) {
    int lane = tid & 63, wv = tid >> 6;
    int s = v;
    #pragma unroll
    for (int off = 1; off < 64; off <<= 1) {
        int t = __shfl_up(s, off, 64);
        if (lane >= off) s += t;
    }
    __shared__ int wsum[4];
    if (lane == 63) wsum[wv] = s;
    __syncthreads();
    #pragma unroll
    for (int w = 0; w < 3; ++w)
        if (wv > w) s += wsum[w];
    return s;
}

__global__ void k_scan_a(const int* __restrict__ cnt, int* __restrict__ rowptr,
                         int* __restrict__ bsum) {
    int i = blockIdx.x * 256 + threadIdx.x;
    int v = (i < N_NODES) ? cnt[i] : 0;
    int s = iscan_block(v, threadIdx.x);
    if (i < N_NODES) rowptr[i] = s - v;
    if (threadIdx.x == 255) bsum[blockIdx.x] = s;
}

__global__ void k_scan_b(int* __restrict__ bsum, int nb) {
    int i = threadIdx.x;
    int v = (i < nb) ? bsum[i] : 0;
    int s = iscan_block(v, i);
    if (i < nb) bsum[i] = s - v;
}

__global__ void k_scan_c(int* __restrict__ rowptr, const int* __restrict__ bsum,
                         int* __restrict__ cursor) {
    int i = blockIdx.x * 256 + threadIdx.x;
    if (i < N_NODES) {
        int r = rowptr[i] + bsum[blockIdx.x];
        rowptr[i] = r;
        cursor[i] = r;
    }
    if (i == 0) rowptr[N_NODES] = N_EDGES;
}

__global__ void k_fill(const int* __restrict__ coli, const int* __restrict__ rowi,
                       int* __restrict__ cursor, int* __restrict__ elist,
                       int* __restrict__ rowg) {
    int e = blockIdx.x * blockDim.x + threadIdx.x;
    if (e < N_EDGES) {
        int p = atomicAdd(&cursor[coli[e]], 1);
        elist[p] = e;
        rowg[p] = rowi[e];
    }
}

// CSR position -> packed (node<<1)|interior
__global__ void k_posnode(const int* __restrict__ rowptr, int* __restrict__ posnode) {
    int p = blockIdx.x * blockDim.x + threadIdx.x;
    if (p >= N_EDGES) return;
    int lo = 0, hi = N_NODES;
    while (hi - lo > 1) {
        int mid = (lo + hi) >> 1;
        if (rowptr[mid] <= p) lo = mid; else hi = mid;
    }
    const int t0 = p & ~63;
    const int inter = (rowptr[lo] >= t0) && (rowptr[lo + 1] <= t0 + 64);
    posnode[p] = (lo << 1) | inter;
}

// ---------------- xw1 = x @ W1a + b1 (f32, fragment-permuted layout) ----------------
__global__ __launch_bounds__(256) void k_xw1(
    const ushort_t* __restrict__ xb, const ushort_t* __restrict__ w1at,
    const float* __restrict__ b1, float* __restrict__ xw1)
{
    __shared__ __align__(16) ushort_t As[64 * 64];
    __shared__ __align__(16) ushort_t Bs[256 * 64];
    const int tid = threadIdx.x;
    const int wave = tid >> 6, lane = tid & 63;
    const int lr = lane & 15, lh = lane >> 4;
    const int n0 = blockIdx.x * 64;

    const int sm = tid >> 2;
    const int sc = (tid & 3) << 4;
    int ns = n0 + sm; if (ns >= N_NODES) ns = N_NODES - 1;
    const ushort_t* xrow = xb + (size_t)ns * D;
    const ushort_t* wrow = w1at + (size_t)tid * D;
    const int swA = (sm & 7) << 3;
    const int swB = (tid & 7) << 3;

    f32x4 acc[4][4];
    #pragma unroll
    for (int i = 0; i < 4; ++i)
        #pragma unroll
        for (int j = 0; j < 4; ++j)
            acc[i][j] = (f32x4){0.f, 0.f, 0.f, 0.f};

    for (int kk = 0; kk < 4; ++kk) {
        const int k0 = kk << 6;
        const uint4* sx = (const uint4*)(xrow + k0 + sc);
        uint4 av0 = sx[0], av1 = sx[1];
        const uint4* wsv = (const uint4*)(wrow + k0);
        uint4 w0 = wsv[0], w1 = wsv[1], w2 = wsv[2], w3 = wsv[3];
        uint4 w4 = wsv[4], w5 = wsv[5], w6 = wsv[6], w7 = wsv[7];

        __syncthreads();
        *(uint4*)&As[sm * 64 + ( sc      ^ swA)] = av0;
        *(uint4*)&As[sm * 64 + ((sc + 8) ^ swA)] = av1;
        {
            const int base = tid * 64;
            *(uint4*)&Bs[base + ( 0 ^ swB)] = w0;
            *(uint4*)&Bs[base + ( 8 ^ swB)] = w1;
            *(uint4*)&Bs[base + (16 ^ swB)] = w2;
            *(uint4*)&Bs[base + (24 ^ swB)] = w3;
            *(uint4*)&Bs[base + (32 ^ swB)] = w4;
            *(uint4*)&Bs[base + (40 ^ swB)] = w5;
            *(uint4*)&Bs[base + (48 ^ swB)] = w6;
            *(uint4*)&Bs[base + (56 ^ swB)] = w7;
        }
        __syncthreads();

        #pragma unroll
        for (int kh = 0; kh < 2; ++kh) {
            const int kb = kh * 32 + lh * 8;
            bf16x8 af[4], bfr[4];
            #pragma unroll
            for (int i = 0; i < 4; ++i) {
                int m = i * 16 + lr;
                af[i] = *(const bf16x8*)&As[m * 64 + (kb ^ ((m & 7) << 3))];
            }
            #pragma unroll
            for (int j = 0; j < 4; ++j) {
                int n = wave * 64 + j * 16 + lr;
                bfr[j] = *(const bf16x8*)&Bs[n * 64 + (kb ^ ((n & 7) << 3))];
            }
            #pragma unroll
            for (int i = 0; i < 4; ++i)
                #pragma unroll
                for (int j = 0; j < 4; ++j)
                    acc[i][j] = __builtin_amdgcn_mfma_f32_16x16x32_bf16(af[i], bfr[j], acc[i][j], 0, 0, 0);
        }
    }

    float bv[4];
    #pragma unroll
    for (int j = 0; j < 4; ++j) bv[j] = b1[wave * 64 + j * 16 + lr];
    #pragma unroll
    for (int i = 0; i < 4; ++i) {
        #pragma unroll
        for (int r = 0; r < 4; ++r) {
            int m = i * 16 + lh * 4 + r;
            int node = n0 + m;
            if (node < N_NODES) {
                float4 v;
                v.x = acc[i][0][r] + bv[0];
                v.y = acc[i][1][r] + bv[1];
                v.z = acc[i][2][r] + bv[2];
                v.w = acc[i][3][r] + bv[3];
                *(float4*)&xw1[(size_t)node * D + (size_t)(wave * 16 + lr) * 4] = v;
            }
        }
    }
}

// ---------------- edge GEMM (K=256) + in-register segmented aggregation ----------------
// R13 semantics; VMEM FIFO restructured so the load queue NEVER drains mid-loop:
//  - ea staging regs ping-pong (st[2][4]): next-next ea issued at step TOP, before
//    the dependent LDS write, so the write's wait is counted vmcnt leaving them in flight.
//  - B prefetched one step ahead (bReg), issued AFTER this step's MFMA consumed it,
//    so MFMA's wait for B forces only the already-flown ea(k+1), never ea(k+2).
__global__ __launch_bounds__(256, 3) void k_edge_csr(
    const float* __restrict__ ea, const ushort_t* __restrict__ w1bt,
    const float* __restrict__ xw1, const int* __restrict__ elist,
    const int* __restrict__ rowg, const int* __restrict__ posnode,
    float* __restrict__ agg)
{
    __shared__ __align__(16) ushort_t As[2][64 * 64];  // 2 x 8KB, ea tiles (bf16)
    __shared__ int snd[64];                            // packed (node<<1)|interior
    const int tid = threadIdx.x;
    const int wave = tid >> 6, lane = tid & 63;
    const int lr = lane & 15, lh = lane >> 4;
    const int p0 = blockIdx.x * 64;

    if (tid < 64) {
        int p = p0 + tid;
        snd[tid] = (p < N_EDGES) ? posnode[min(p, N_EDGES - 1)] : -1;
    }

    const int sm = tid >> 2;           // A row staged by this thread
    const int sc = (tid & 3) << 4;     // 16-elem chunk within 64-elem K-step
    int ps = p0 + sm; if (ps >= N_EDGES) ps = N_EDGES - 1;
    const float* earow = ea + (size_t)elist[ps] * D;
    const int swA = (sm & 7) << 3;

    // B row pointers: col n = wave*64 + j*16 + lr, pre-offset by lane k-phase
    const ushort_t* pw[4];
    #pragma unroll
    for (int j = 0; j < 4; ++j)
        pw[j] = w1bt + (size_t)(wave * 64 + j * 16 + lr) * D + lh * 8;

    f32x4 acc[4][4];
    #pragma unroll
    for (int i = 0; i < 4; ++i)
        #pragma unroll
        for (int j = 0; j < 4; ++j)
            acc[i][j] = (f32x4){0.f, 0.f, 0.f, 0.f};

    float4 st[2][4];      // ea staging ping-pong (static indexing: loop fully unrolled)
    bf16x8 bReg[8];       // B for current step (prefetched one step ahead)

    // ---- prologue: issue ea0, ea1, B0; write step0; barrier ----
    {
        const float4* s = (const float4*)(earow + sc);
        st[0][0] = s[0]; st[0][1] = s[1]; st[0][2] = s[2]; st[0][3] = s[3];
    }
    {
        const float4* s = (const float4*)(earow + 64 + sc);
        st[1][0] = s[0]; st[1][1] = s[1]; st[1][2] = s[2]; st[1][3] = s[3];
    }
    #pragma unroll
    for (int j = 0; j < 4; ++j) {
        bReg[j]     = *(const bf16x8*)(pw[j]);
        bReg[4 + j] = *(const bf16x8*)(pw[j] + 32);
    }
    {
        // waits only for ea0 (oldest); ea1 + B0 stay in flight
        uint4 av0, av1;
        av0.x = pk2(st[0][0].x, st[0][0].y); av0.y = pk2(st[0][0].z, st[0][0].w);
        av0.z = pk2(st[0][1].x, st[0][1].y); av0.w = pk2(st[0][1].z, st[0][1].w);
        av1.x = pk2(st[0][2].x, st[0][2].y); av1.y = pk2(st[0][2].z, st[0][2].w);
        av1.z = pk2(st[0][3].x, st[0][3].y); av1.w = pk2(st[0][3].z, st[0][3].w);
        *(uint4*)&As[0][sm * 64 + ( sc      ^ swA)] = av0;
        *(uint4*)&As[0][sm * 64 + ((sc + 8) ^ swA)] = av1;
    }
    barrier_nodrain();

    // ---- K-loop: 4 steps of 64 ----
    #pragma unroll
    for (int kk = 0; kk < 4; ++kk) {
        // (1) issue ea for step kk+2 into the just-freed staging set (youngest in FIFO)
        if (kk < 2) {
            const float4* s = (const float4*)(earow + ((kk + 2) << 6) + sc);
            st[kk & 1][0] = s[0]; st[kk & 1][1] = s[1];
            st[kk & 1][2] = s[2]; st[kk & 1][3] = s[3];
        }

        // (2) LDS reads for this step
        const ushort_t* cur = As[kk & 1];
        bf16x8 af0[4], af1[4];
        #pragma unroll
        for (int i = 0; i < 4; ++i) {
            const int m = i * 16 + lr;
            const int sw = (m & 7) << 3;
            af0[i] = *(const bf16x8*)&cur[m * 64 + (( lh * 8     ) ^ sw)];
            af1[i] = *(const bf16x8*)&cur[m * 64 + ((32 + lh * 8) ^ sw)];
        }

        // (3) MFMA with prefetched B (waiting for it retires at most ea[kk+1], never ea[kk+2])
        #pragma unroll
        for (int i = 0; i < 4; ++i)
            #pragma unroll
            for (int j = 0; j < 4; ++j) {
                acc[i][j] = __builtin_amdgcn_mfma_f32_16x16x32_bf16(af0[i], bReg[j],     acc[i][j], 0, 0, 0);
                acc[i][j] = __builtin_amdgcn_mfma_f32_16x16x32_bf16(af1[i], bReg[4 + j], acc[i][j], 0, 0, 0);
            }

        if (kk < 3) {
            // (4) issue B for step kk+1 (bReg consumed by MFMA above)
            const int kn = (kk + 1) << 6;
            #pragma unroll
            for (int j = 0; j < 4; ++j) {
                bReg[j]     = *(const bf16x8*)(pw[j] + kn);
                bReg[4 + j] = *(const bf16x8*)(pw[j] + kn + 32);
            }
            // (5) write step kk+1 staging regs to the other LDS buffer
            //     (ea[kk+1] already retired by MFMA's wait; B[kk+1]+ea[kk+2] keep flying)
            uint4 av0, av1;
            const int sB = (kk + 1) & 1;
            av0.x = pk2(st[sB][0].x, st[sB][0].y); av0.y = pk2(st[sB][0].z, st[sB][0].w);
            av0.z = pk2(st[sB][1].x, st[sB][1].y); av0.w = pk2(st[sB][1].z, st[sB][1].w);
            av1.x = pk2(st[sB][2].x, st[sB][2].y); av1.y = pk2(st[sB][2].z, st[sB][2].w);
            av1.z = pk2(st[sB][3].x, st[sB][3].y); av1.w = pk2(st[sB][3].z, st[sB][3].w);
            ushort_t* nxt = (ushort_t*)As[sB];
            *(uint4*)&nxt[sm * 64 + ( sc      ^ swA)] = av0;
            *(uint4*)&nxt[sm * 64 + ((sc + 8) ^ swA)] = av1;
            // (6) barrier (non-draining)
            barrier_nodrain();
        }
    }

    // ---- epilogue 1: add gathered xw1[src] (one float4 per (i,r)), relu ----
    #pragma unroll
    for (int i = 0; i < 4; ++i) {
        #pragma unroll
        for (int r = 0; r < 4; ++r) {
            const int m = i * 16 + lh * 4 + r;
            const bool ok = (p0 + m < N_EDGES);
            const int srw = rowg[min(p0 + m, N_EDGES - 1)];
            const float4 xv = *(const float4*)&xw1[(size_t)srw * D + (size_t)(wave * 16 + lr) * 4];
            const float xvv[4] = {xv.x, xv.y, xv.z, xv.w};
            #pragma unroll
            for (int j = 0; j < 4; ++j) {
                float v = acc[i][j][r] + xvv[j];
                v = v > 0.f ? v : 0.f;
                acc[i][j][r] = ok ? v : 0.f;
            }
        }
    }

    // ---- epilogue 2: block-uniform segment loop, in-register reduce (proven) ----
    int a = 0;
    while (a < 64) {
        const int raw = snd[a];
        int b = a + 1;
        while (b < 64 && snd[b] == raw) ++b;
        if (raw >= 0) {
            const int node = raw >> 1;
            const int interior = raw & 1;
            float s0 = 0.f, s1 = 0.f, s2 = 0.f, s3 = 0.f;
            #pragma unroll
            for (int i = 0; i < 4; ++i) {
                if (b <= i * 16 || a >= (i + 1) * 16) continue;  // uniform skip
                #pragma unroll
                for (int r = 0; r < 4; ++r) {
                    const int m = i * 16 + lh * 4 + r;
                    const bool in = (m >= a) && (m < b);
                    s0 += in ? acc[i][0][r] : 0.f;
                    s1 += in ? acc[i][1][r] : 0.f;
                    s2 += in ? acc[i][2][r] : 0.f;
                    s3 += in ? acc[i][3][r] : 0.f;
                }
            }
            // fold the 4 lh groups (lanes differ in bits 4,5)
            s0 += __shfl_xor(s0, 16, 64); s0 += __shfl_xor(s0, 32, 64);
            s1 += __shfl_xor(s1, 16, 64); s1 += __shfl_xor(s1, 32, 64);
            s2 += __shfl_xor(s2, 16, 64); s2 += __shfl_xor(s2, 32, 64);
            s3 += __shfl_xor(s3, 16, 64); s3 += __shfl_xor(s3, 32, 64);
            if (lh == 0) {
                float* dst = agg + (size_t)node * D + wave * 64 + lr;
                if (interior) {
                    dst[0]  = s0; dst[16] = s1; dst[32] = s2; dst[48] = s3;
                } else {
                    atomicAdd(&dst[0],  s0); atomicAdd(&dst[16], s1);
                    atomicAdd(&dst[32], s2); atomicAdd(&dst[48], s3);
                }
            }
        }
        a = b;
    }
}

// ---------------- node GEMM ----------------
// out[i][n] = relu( concat(x[i], agg[i]/max(cnt,1)) @ W2 + b2 )
__global__ __launch_bounds__(256) void k_node(
    const ushort_t* __restrict__ xb, const float* __restrict__ agg,
    const int* __restrict__ cnti,
    const ushort_t* __restrict__ w2t, const float* __restrict__ b2,
    float* __restrict__ out)
{
    __shared__ __align__(16) ushort_t As[64 * 64];
    __shared__ __align__(16) ushort_t Bs[256 * 64];
    const int tid = threadIdx.x;
    const int wave = tid >> 6, lane = tid & 63;
    const int lr = lane & 15, lh = lane >> 4;
    const int n0 = blockIdx.x * 64;

    const int sm = tid >> 2;
    const int sc = (tid & 3) << 4;
    int ns = n0 + sm; if (ns >= N_NODES) ns = N_NODES - 1;
    const ushort_t* xrow = xb + (size_t)ns * D;
    const float*    arow = agg + (size_t)ns * D;
    const float     ic   = 1.0f / fmaxf((float)cnti[ns], 1.0f);
    const ushort_t* wrow = w2t + (size_t)tid * TWO_D;
    const int swA = (sm & 7) << 3;
    const int swB = (tid & 7) << 3;

    f32x4 acc[4][4];
    #pragma unroll
    for (int i = 0; i < 4; ++i)
        #pragma unroll
        for (int j = 0; j < 4; ++j)
            acc[i][j] = (f32x4){0.f, 0.f, 0.f, 0.f};

    for (int kk = 0; kk < 8; ++kk) {
        const int k0 = kk << 6;
        uint4 av0, av1;
        if (kk < 4) {
            const uint4* s = (const uint4*)(xrow + k0 + sc);
            av0 = s[0]; av1 = s[1];
        } else {
            const float4* s = (const float4*)(arow + (k0 - D) + sc);
            float4 f0 = s[0], f1 = s[1], f2 = s[2], f3 = s[3];
            f0.x *= ic; f0.y *= ic; f0.z *= ic; f0.w *= ic;
            f1.x *= ic; f1.y *= ic; f1.z *= ic; f1.w *= ic;
            f2.x *= ic; f2.y *= ic; f2.z *= ic; f2.w *= ic;
            f3.x *= ic; f3.y *= ic; f3.z *= ic; f3.w *= ic;
            av0.x = pk2(f0.x, f0.y); av0.y = pk2(f0.z, f0.w);
            av0.z = pk2(f1.x, f1.y); av0.w = pk2(f1.z, f1.w);
            av1.x = pk2(f2.x, f2.y); av1.y = pk2(f2.z, f2.w);
            av1.z = pk2(f3.x, f3.y); av1.w = pk2(f3.z, f3.w);
        }
        const uint4* wsv = (const uint4*)(wrow + k0);
        uint4 w0 = wsv[0], w1 = wsv[1], w2 = wsv[2], w3 = wsv[3];
        uint4 w4 = wsv[4], w5 = wsv[5], w6 = wsv[6], w7 = wsv[7];

        barrier_nodrain();
        *(uint4*)&As[sm * 64 + ( sc      ^ swA)] = av0;
        *(uint4*)&As[sm * 64 + ((sc + 8) ^ swA)] = av1;
        {
            const int base = tid * 64;
            *(uint4*)&Bs[base + ( 0 ^ swB)] = w0;
            *(uint4*)&Bs[base + ( 8 ^ swB)] = w1;
            *(uint4*)&Bs[base + (16 ^ swB)] = w2;
            *(uint4*)&Bs[base + (24 ^ swB)] = w3;
            *(uint4*)&Bs[base + (32 ^ swB)] = w4;
            *(uint4*)&Bs[base + (40 ^ swB)] = w5;
            *(uint4*)&Bs[base + (48 ^ swB)] = w6;
            *(uint4*)&Bs[base + (56 ^ swB)] = w7;
        }
        barrier_nodrain();

        #pragma unroll
        for (int kh = 0; kh < 2; ++kh) {
            const int kb = kh * 32 + lh * 8;
            bf16x8 af[4], bfr[4];
            #pragma unroll
            for (int i = 0; i < 4; ++i) {
                int m = i * 16 + lr;
                af[i] = *(const bf16x8*)&As[m * 64 + (kb ^ ((m & 7) << 3))];
            }
            #pragma unroll
            for (int j = 0; j < 4; ++j) {
                int n = wave * 64 + j * 16 + lr;
                bfr[j] = *(const bf16x8*)&Bs[n * 64 + (kb ^ ((n & 7) << 3))];
            }
            #pragma unroll
            for (int i = 0; i < 4; ++i)
                #pragma unroll
                for (int j = 0; j < 4; ++j)
                    acc[i][j] = __builtin_amdgcn_mfma_f32_16x16x32_bf16(af[i], bfr[j], acc[i][j], 0, 0, 0);
        }
    }

    float bv[4];
    #pragma unroll
    for (int j = 0; j < 4; ++j) bv[j] = b2[wave * 64 + j * 16 + lr];
    #pragma unroll
    for (int i = 0; i < 4; ++i) {
        #pragma unroll
        for (int r = 0; r < 4; ++r) {
            int m = i * 16 + lh * 4 + r;
            int node = n0 + m;
            if (node < N_NODES) {
                float* orow = out + (size_t)node * D;
                #pragma unroll
                for (int j = 0; j < 4; ++j) {
                    float v = acc[i][j][r] + bv[j];
                    orow[wave * 64 + j * 16 + lr] = v > 0.f ? v : 0.f;
                }
            }
        }
    }
}

// ---------------- launch ----------------

extern "C" void kernel_launch(void* const* d_in, const int* in_sizes, int n_in,
                              void* d_out, int out_size, void* d_ws, size_t ws_size,
                              hipStream_t stream)
{
    const float* x  = (const float*)d_in[0];
    const int*   ei = (const int*)d_in[1];      // [2*E] int32: rows then cols
    const float* ea = (const float*)d_in[2];
    const float* W1 = (const float*)d_in[5];
    const float* b1 = (const float*)d_in[6];
    const float* W2 = (const float*)d_in[7];
    const float* b2 = (const float*)d_in[8];
    float* out = (float*)d_out;

    const int* rowi = ei;
    const int* coli = ei + N_EDGES;
    char* ws = (char*)d_ws;

    size_t off = 0;
    auto take = [&](size_t bytes) {
        char* p = ws + off;
        off = (off + bytes + 255) & ~(size_t)255;
        return p;
    };

    ushort_t* xb      = (ushort_t*)take((size_t)N_NODES * D * 2);
    ushort_t* w1at    = (ushort_t*)take((size_t)D * D * 2);
    ushort_t* w1bt    = (ushort_t*)take((size_t)D * D * 2);
    ushort_t* w2t     = (ushort_t*)take((size_t)D * TWO_D * 2);
    float*    xw1     = (float*)take((size_t)N_NODES * D * 4);
    float*    agg     = (float*)take((size_t)N_NODES * D * 4);
    int*      cnti    = (int*)take(50016 * 4);
    int*      rowptr  = (int*)take(50016 * 4);
    int*      cursor  = (int*)take(50016 * 4);
    int*      bsum    = (int*)take(256 * 4);
    int*      elist   = (int*)take((size_t)N_EDGES * 4);
    int*      rowg    = (int*)take((size_t)N_EDGES * 4);
    int*      posnode = (int*)take((size_t)N_EDGES * 4);

    const int NB = (N_NODES + 255) / 256;          // 196
    const int EB = (N_EDGES + 255) / 256;          // 1954
    const int NGB = (N_NODES + 63) / 64;           // 782
    const int EGB = (N_EDGES + 63) / 64;           // 7813

    k_cvt_x<<<(N_NODES * D / 8 + 255) / 256, 256, 0, stream>>>(x, xb, N_NODES * D / 8);
    k_wt   <<<D, 256, 0, stream>>>(W1, w1at, D);
    k_wt   <<<D, 256, 0, stream>>>(W1 + (size_t)D * D, w1bt, D);
    k_wt   <<<D, 256, 0, stream>>>(W2, w2t, TWO_D);

    k_zero   <<<49, 256, 0, stream>>>((float*)cnti, 50016 / 4);
    k_count_i<<<EB, 256, 0, stream>>>(coli, cnti);
    k_scan_a <<<NB, 256, 0, stream>>>(cnti, rowptr, bsum);
    k_scan_b <<<1, 256, 0, stream>>>(bsum, NB);
    k_scan_c <<<NB, 256, 0, stream>>>(rowptr, bsum, cursor);
    k_fill   <<<EB, 256, 0, stream>>>(coli, rowi, cursor, elist, rowg);
    k_posnode<<<EB, 256, 0, stream>>>(rowptr, posnode);

    k_xw1    <<<NGB, 256, 0, stream>>>(xb, w1at, b1, xw1);
    k_zero   <<<(N_NODES * D / 4 + 255) / 256, 256, 0, stream>>>(agg, N_NODES * D / 4);
    k_edge_csr<<<EGB, 256, 0, stream>>>(ea, w1bt, xw1, elist, rowg, posnode, agg);
    k_node   <<<NGB, 256, 0, stream>>>(xb, agg, cnti, w2t, b2, out);
}